// Round 4
// baseline (706.952 us; speedup 1.0000x reference)
//
#include <hip/hip_runtime.h>
#include <hip/hip_bf16.h>

#define NEG_SLOPE 0.2f
#define BN_EPS 1e-5f

typedef __attribute__((ext_vector_type(8))) short bf16x8;
typedef __attribute__((ext_vector_type(4))) float f32x4;
typedef __attribute__((ext_vector_type(8))) unsigned short u16x8;

__device__ __forceinline__ float bf2f(unsigned short u) {
    union { unsigned int i; float f; } x;
    x.i = ((unsigned int)u) << 16;
    return x.f;
}
__device__ __forceinline__ unsigned short f2bf(float f) {
    __hip_bfloat16 b = __float2bfloat16(f);
    return *reinterpret_cast<unsigned short*>(&b);
}
__device__ __forceinline__ float lrelu(float v) {
    return v > 0.f ? v : NEG_SLOPE * v;
}

// ---------------------------------------------------------------- CSR build
__global__ __launch_bounds__(256) void count_kernel(const int* __restrict__ dstl,
                                                    int E, int N, int* __restrict__ counts) {
    int i = blockIdx.x * 256 + threadIdx.x;
    if (i < E + N) {
        int d = (i < E) ? dstl[i] : (i - E);
        atomicAdd(&counts[d], 1);
    }
}

__device__ __forceinline__ int block_scan_incl(int v, int t) {
    int lane = t & 63, w = t >> 6;
    int sv = v;
    #pragma unroll
    for (int off = 1; off < 64; off <<= 1) {
        int u = __shfl_up(sv, off);
        if (lane >= off) sv += u;
    }
    __shared__ int ws[4];
    if (lane == 63) ws[w] = sv;
    __syncthreads();
    if (t == 0) {
        int a = 0;
        #pragma unroll
        for (int k = 0; k < 4; k++) { int x = ws[k]; ws[k] = a; a += x; }
    }
    __syncthreads();
    return sv + ws[w];
}

__global__ __launch_bounds__(256) void scan1(const int* __restrict__ counts,
                                             int* __restrict__ tmp,
                                             int* __restrict__ bsums, int n) {
    int t = threadIdx.x, i = blockIdx.x * 256 + t;
    int v = (i < n) ? counts[i] : 0;
    int incl = block_scan_incl(v, t);
    if (i < n) tmp[i] = incl;
    if (t == 255) bsums[blockIdx.x] = incl;
}

__global__ __launch_bounds__(256) void scan2(int* __restrict__ bsums, int nb) {
    int t = threadIdx.x;
    int v = (t < nb) ? bsums[t] : 0;
    int incl = block_scan_incl(v, t);
    if (t < nb) bsums[t] = incl - v;
}

__global__ __launch_bounds__(256) void scan3(const int* __restrict__ tmp,
                                             const int* __restrict__ bsums,
                                             const int* __restrict__ counts,
                                             int* __restrict__ indptr,
                                             int* __restrict__ cursor, int n) {
    int i = blockIdx.x * 256 + threadIdx.x;
    if (i < n) {
        int incl = tmp[i] + bsums[i >> 8];
        indptr[i + 1] = incl;
        cursor[i] = incl - counts[i];
        if (i == 0) indptr[0] = 0;
    }
}

__global__ __launch_bounds__(256) void fill_kernel(const int* __restrict__ srcl,
                                                   const int* __restrict__ dstl,
                                                   int E, int N,
                                                   int* __restrict__ cursor,
                                                   int* __restrict__ esrc) {
    int i = blockIdx.x * 256 + threadIdx.x;
    if (i < E + N) {
        int s, d;
        if (i < E) { s = srcl[i]; d = dstl[i]; }
        else       { s = d = i - E; }
        int slot = atomicAdd(&cursor[d], 1);
        esrc[slot] = s;
    }
}

// ---------------------------------------------------------------- converts
__global__ __launch_bounds__(256) void f32_to_bf16(const float* __restrict__ src,
                                                   unsigned short* __restrict__ dst, int n4) {
    int i = blockIdx.x * 256 + threadIdx.x;
    if (i < n4) {
        float4 v = reinterpret_cast<const float4*>(src)[i];
        ushort4 o;
        o.x = f2bf(v.x); o.y = f2bf(v.y); o.z = f2bf(v.z); o.w = f2bf(v.w);
        reinterpret_cast<ushort4*>(dst)[i] = o;
    }
}

// W[K x M] fp32 -> Wt[M x K] bf16
__global__ __launch_bounds__(256) void transpose_bf16(const float* __restrict__ src,
                                                      unsigned short* __restrict__ dst,
                                                      int K, int M) {
    int i = blockIdx.x * 256 + threadIdx.x;
    if (i < K * M) {
        int m = i / K, k = i - m * K;
        dst[i] = f2bf(src[(size_t)k * M + m]);
    }
}

// ---------------------------------------------------------------- bf16 MFMA GEMM
// C[M x NC] = A[M x K](bf16) @ B, Bt[NC x K](bf16) = B^T. Block: 64 rows x NCT cols.
// NCT == NC => A fetched exactly once.
template <int NCT, typename OutT>
__global__ __launch_bounds__(256) void gemm_bf16(const unsigned short* __restrict__ A,
                                                 const unsigned short* __restrict__ Bt,
                                                 const float* __restrict__ bias,
                                                 OutT* __restrict__ C,
                                                 int M, int K, int NC) {
    constexpr int NF = NCT / 16;
    int t = threadIdx.x;
    int w = t >> 6, lane = t & 63;
    int l16 = lane & 15, quad = lane >> 4;
    int rowBase = blockIdx.y * 64 + w * 16;
    int colBase = blockIdx.x * NCT;

    f32x4 acc[NF];
    #pragma unroll
    for (int f = 0; f < NF; f++) acc[f] = (f32x4){0.f, 0.f, 0.f, 0.f};

    int arow = rowBase + l16;
    if (arow >= M) arow = M - 1;
    const unsigned short* aptr = A + (size_t)arow * K + quad * 8;

    for (int k0 = 0; k0 < K; k0 += 32) {
        bf16x8 af = *reinterpret_cast<const bf16x8*>(aptr + k0);
        #pragma unroll
        for (int f = 0; f < NF; f++) {
            int col = colBase + f * 16 + l16;
            bf16x8 bf = *reinterpret_cast<const bf16x8*>(&Bt[(size_t)col * K + k0 + quad * 8]);
            acc[f] = __builtin_amdgcn_mfma_f32_16x16x32_bf16(af, bf, acc[f], 0, 0, 0);
        }
    }

    #pragma unroll
    for (int f = 0; f < NF; f++) {
        int col = colBase + f * 16 + l16;
        float bv = bias ? bias[col] : 0.f;
        #pragma unroll
        for (int r = 0; r < 4; r++) {
            int row = rowBase + quad * 4 + r;
            if (row < M) {
                float v = acc[f][r] + bv;
                if constexpr (sizeof(OutT) == 2) C[(size_t)row * NC + col] = (OutT)f2bf(v);
                else                             C[(size_t)row * NC + col] = v;
            }
        }
    }
}

// ---------------------------------------------------------------- alpha (H=8,C=32), wave/node
__global__ __launch_bounds__(256) void alpha256(const unsigned short* __restrict__ h,
                                                const float* __restrict__ a_s,
                                                const float* __restrict__ a_d,
                                                float* __restrict__ as_out,
                                                float* __restrict__ ad_out, int N) {
    int t = threadIdx.x;
    int n = blockIdx.x * 4 + (t >> 6);
    if (n >= N) return;
    int lane = t & 63, lane4 = lane * 4;
    ushort4 hv = *reinterpret_cast<const ushort4*>(&h[(size_t)n * 256 + lane4]);
    float4 sv = *reinterpret_cast<const float4*>(&a_s[lane4]);
    float4 dv = *reinterpret_cast<const float4*>(&a_d[lane4]);
    float h0 = bf2f(hv.x), h1 = bf2f(hv.y), h2 = bf2f(hv.z), h3 = bf2f(hv.w);
    float va = h0 * sv.x + h1 * sv.y + h2 * sv.z + h3 * sv.w;
    float vd = h0 * dv.x + h1 * dv.y + h2 * dv.z + h3 * dv.w;
    #pragma unroll
    for (int off = 1; off < 8; off <<= 1) {
        va += __shfl_xor(va, off);
        vd += __shfl_xor(vd, off);
    }
    if ((lane & 7) == 0) {
        as_out[n * 8 + (lane >> 3)] = va;
        ad_out[n * 8 + (lane >> 3)] = vd;
    }
}

// ---------------------------------------------------------------- alpha (H=1,C=32), 8 nodes/wave
__global__ __launch_bounds__(256) void alpha32(const unsigned short* __restrict__ h,
                                               const float* __restrict__ a_s,
                                               const float* __restrict__ a_d,
                                               float* __restrict__ as_out,
                                               float* __restrict__ ad_out, int N) {
    int t = threadIdx.x;
    int lane = t & 63;
    int n = blockIdx.x * 32 + (t >> 6) * 8 + (lane >> 3);
    int c4 = (lane & 7) * 4;
    if (n >= N) return;
    ushort4 hv = *reinterpret_cast<const ushort4*>(&h[(size_t)n * 32 + c4]);
    float4 sv = *reinterpret_cast<const float4*>(&a_s[c4]);
    float4 dv = *reinterpret_cast<const float4*>(&a_d[c4]);
    float h0 = bf2f(hv.x), h1 = bf2f(hv.y), h2 = bf2f(hv.z), h3 = bf2f(hv.w);
    float va = h0 * sv.x + h1 * sv.y + h2 * sv.z + h3 * sv.w;
    float vd = h0 * dv.x + h1 * dv.y + h2 * dv.z + h3 * dv.w;
    #pragma unroll
    for (int off = 1; off < 8; off <<= 1) {
        va += __shfl_xor(va, off);
        vd += __shfl_xor(vd, off);
    }
    if ((lane & 7) == 0) {
        as_out[n] = va;
        ad_out[n] = vd;
    }
}

// ---------------------------------------------------------------- aggregation H=8,C=32
// One wave per node, single pass (no max-shift), 16 edges / 8KB in flight per iter.
// Weight lanes: lane = e_sub*8 + h_sub. Gather lanes: half = lane>>5, c8 = lane&31
// (channels c8*8..+7, ushort8 = 16B; one load inst covers an edge pair).
template <int MODE>
__global__ __launch_bounds__(256) void agg256(const unsigned short* __restrict__ hfeat,
                                              const float* __restrict__ as,
                                              const float* __restrict__ ad,
                                              const int* __restrict__ indptr,
                                              const int* __restrict__ esrc,
                                              const float* __restrict__ bias,
                                              const float* __restrict__ bn_g,
                                              const float* __restrict__ bn_b,
                                              const float* __restrict__ bn_m,
                                              const float* __restrict__ bn_v,
                                              const float* __restrict__ skip,
                                              unsigned short* __restrict__ out, int N) {
    int t = threadIdx.x;
    int n = blockIdx.x * 4 + (t >> 6);
    if (n >= N) return;
    int lane = t & 63;
    int e_sub = lane >> 3, h_sub = lane & 7;   // weight mapping
    int half = lane >> 5, c8 = lane & 31;      // gather mapping
    int ch_head = c8 >> 2;                     // head of channels c8*8..+7
    int start = indptr[n], end = indptr[n + 1];
    int cnt = end - start;

    float adh = ad[n * 8 + h_sub];

    float accs[8];
    #pragma unroll
    for (int k = 0; k < 8; k++) accs[k] = 0.f;
    float sm = 0.f;

    int nfull = cnt & ~15;
    int i0 = start;
    for (; i0 < start + nfull; i0 += 16) {
        int sA = esrc[i0 + e_sub];
        int sB = esrc[i0 + 8 + e_sub];
        float wA = __expf(lrelu(as[sA * 8 + h_sub] + adh));
        float wB = __expf(lrelu(as[sB * 8 + h_sub] + adh));
        sm += wA + wB;
        int se[16]; float we[16];
        #pragma unroll
        for (int e = 0; e < 8; e++) {
            se[e]     = __shfl(sA, e * 8);
            se[8 + e] = __shfl(sB, e * 8);
            we[e]     = __shfl(wA, e * 8 + ch_head);
            we[8 + e] = __shfl(wB, e * 8 + ch_head);
        }
        u16x8 hv[8];
        #pragma unroll
        for (int j = 0; j < 8; j++) {
            int s = half ? se[2 * j + 1] : se[2 * j];
            hv[j] = *reinterpret_cast<const u16x8*>(&hfeat[(size_t)s * 256 + c8 * 8]);
        }
        #pragma unroll
        for (int j = 0; j < 8; j++) {
            float w = half ? we[2 * j + 1] : we[2 * j];
            #pragma unroll
            for (int k = 0; k < 8; k++)
                accs[k] = fmaf(w, bf2f(hv[j][k]), accs[k]);
        }
    }
    int rem = cnt - nfull;
    if (rem) {
        int idxA = i0 + e_sub, idxB = i0 + 8 + e_sub;
        int sA = esrc[idxA < end ? idxA : end - 1];
        int sB = esrc[idxB < end ? idxB : end - 1];
        float wA = (idxA < end) ? __expf(lrelu(as[sA * 8 + h_sub] + adh)) : 0.f;
        float wB = (idxB < end) ? __expf(lrelu(as[sB * 8 + h_sub] + adh)) : 0.f;
        sm += wA + wB;
        int se[16]; float we[16];
        #pragma unroll
        for (int e = 0; e < 8; e++) {
            se[e]     = __shfl(sA, e * 8);
            se[8 + e] = __shfl(sB, e * 8);
            we[e]     = __shfl(wA, e * 8 + ch_head);
            we[8 + e] = __shfl(wB, e * 8 + ch_head);
        }
        #pragma unroll
        for (int j = 0; j < 8; j++) {
            int e = 2 * j + half;
            if (e < rem) {
                int s  = half ? se[2 * j + 1] : se[2 * j];
                float w = half ? we[2 * j + 1] : we[2 * j];
                u16x8 hv = *reinterpret_cast<const u16x8*>(&hfeat[(size_t)s * 256 + c8 * 8]);
                #pragma unroll
                for (int k = 0; k < 8; k++)
                    accs[k] = fmaf(w, bf2f(hv[k]), accs[k]);
            }
        }
    }

    // denominators (per head) and half-combine
    #pragma unroll
    for (int off = 8; off < 64; off <<= 1) sm += __shfl_xor(sm, off);
    float il = 1.f / (sm + 1e-16f);
    float il_c = __shfl(il, ch_head);
    #pragma unroll
    for (int k = 0; k < 8; k++) accs[k] += __shfl_xor(accs[k], 32);

    if (lane < 32) {
        int cb = lane * 8;
        float4 b0  = *reinterpret_cast<const float4*>(&bias[cb]);
        float4 b1  = *reinterpret_cast<const float4*>(&bias[cb + 4]);
        float4 g0  = *reinterpret_cast<const float4*>(&bn_g[cb]);
        float4 g1  = *reinterpret_cast<const float4*>(&bn_g[cb + 4]);
        float4 bb0 = *reinterpret_cast<const float4*>(&bn_b[cb]);
        float4 bb1 = *reinterpret_cast<const float4*>(&bn_b[cb + 4]);
        float4 m0  = *reinterpret_cast<const float4*>(&bn_m[cb]);
        float4 m1  = *reinterpret_cast<const float4*>(&bn_m[cb + 4]);
        float4 v0  = *reinterpret_cast<const float4*>(&bn_v[cb]);
        float4 v1  = *reinterpret_cast<const float4*>(&bn_v[cb + 4]);
        float bia[8] = {b0.x, b0.y, b0.z, b0.w, b1.x, b1.y, b1.z, b1.w};
        float g[8]   = {g0.x, g0.y, g0.z, g0.w, g1.x, g1.y, g1.z, g1.w};
        float bb[8]  = {bb0.x, bb0.y, bb0.z, bb0.w, bb1.x, bb1.y, bb1.z, bb1.w};
        float m[8]   = {m0.x, m0.y, m0.z, m0.w, m1.x, m1.y, m1.z, m1.w};
        float vr[8]  = {v0.x, v0.y, v0.z, v0.w, v1.x, v1.y, v1.z, v1.w};
        float sk[8] = {0.f, 0.f, 0.f, 0.f, 0.f, 0.f, 0.f, 0.f};
        if (MODE == 1) {
            float4 s0 = *reinterpret_cast<const float4*>(&skip[(size_t)n * 256 + cb]);
            float4 s1 = *reinterpret_cast<const float4*>(&skip[(size_t)n * 256 + cb + 4]);
            sk[0] = s0.x; sk[1] = s0.y; sk[2] = s0.z; sk[3] = s0.w;
            sk[4] = s1.x; sk[5] = s1.y; sk[6] = s1.z; sk[7] = s1.w;
        }
        u16x8 res;
        #pragma unroll
        for (int k = 0; k < 8; k++) {
            float val = accs[k] * il_c + bia[k];
            val = (val - m[k]) * rsqrtf(vr[k] + BN_EPS) * g[k] + bb[k];
            val = val > 0.f ? val : (__expf(val) - 1.f);
            val += sk[k];
            res[k] = f2bf(val);
        }
        *reinterpret_cast<u16x8*>(&out[(size_t)n * 256 + cb]) = res;
    }
}

// ---------------------------------------------------------------- aggregation H=1,C=32
// One wave per node; lane = e_sub*8 + c_sub; single pass, 16 edges in flight.
__global__ __launch_bounds__(256) void agg32(const unsigned short* __restrict__ h3,
                                             const float* __restrict__ as,
                                             const float* __restrict__ ad,
                                             const int* __restrict__ indptr,
                                             const int* __restrict__ esrc,
                                             const float* __restrict__ b3,
                                             const float* __restrict__ xs,
                                             float* __restrict__ out, int N) {
    int t = threadIdx.x;
    int n = blockIdx.x * 4 + (t >> 6);
    if (n >= N) return;
    int lane = t & 63;
    int e_sub = lane >> 3, c4 = (lane & 7) * 4;
    int start = indptr[n], end = indptr[n + 1];
    float adn = ad[n];

    float4 acc = make_float4(0.f, 0.f, 0.f, 0.f);
    float sm = 0.f;
    int i0 = start;
    for (; i0 + 16 <= end; i0 += 16) {
        int sA = esrc[i0 + e_sub];
        int sB = esrc[i0 + 8 + e_sub];
        float wA = __expf(lrelu(as[sA] + adn));
        float wB = __expf(lrelu(as[sB] + adn));
        sm += wA + wB;
        ushort4 hA = *reinterpret_cast<const ushort4*>(&h3[(size_t)sA * 32 + c4]);
        ushort4 hB = *reinterpret_cast<const ushort4*>(&h3[(size_t)sB * 32 + c4]);
        acc.x = fmaf(wA, bf2f(hA.x), acc.x); acc.y = fmaf(wA, bf2f(hA.y), acc.y);
        acc.z = fmaf(wA, bf2f(hA.z), acc.z); acc.w = fmaf(wA, bf2f(hA.w), acc.w);
        acc.x = fmaf(wB, bf2f(hB.x), acc.x); acc.y = fmaf(wB, bf2f(hB.y), acc.y);
        acc.z = fmaf(wB, bf2f(hB.z), acc.z); acc.w = fmaf(wB, bf2f(hB.w), acc.w);
    }
    for (; i0 < end; i0 += 8) {
        int idx = i0 + e_sub;
        bool valid = idx < end;
        if (valid) {
            int s = esrc[idx];
            float w = __expf(lrelu(as[s] + adn));
            sm += w;
            ushort4 hv = *reinterpret_cast<const ushort4*>(&h3[(size_t)s * 32 + c4]);
            acc.x = fmaf(w, bf2f(hv.x), acc.x);
            acc.y = fmaf(w, bf2f(hv.y), acc.y);
            acc.z = fmaf(w, bf2f(hv.z), acc.z);
            acc.w = fmaf(w, bf2f(hv.w), acc.w);
        }
    }
    #pragma unroll
    for (int off = 8; off < 64; off <<= 1) {
        sm    += __shfl_xor(sm, off);
        acc.x += __shfl_xor(acc.x, off);
        acc.y += __shfl_xor(acc.y, off);
        acc.z += __shfl_xor(acc.z, off);
        acc.w += __shfl_xor(acc.w, off);
    }
    if (e_sub == 0) {
        float il = 1.f / (sm + 1e-16f);
        float4 bv = *reinterpret_cast<const float4*>(&b3[c4]);
        float4 xv = *reinterpret_cast<const float4*>(&xs[(size_t)n * 32 + c4]);
        float4 o;
        o.x = acc.x * il + bv.x + xv.x;
        o.y = acc.y * il + bv.y + xv.y;
        o.z = acc.z * il + bv.z + xv.z;
        o.w = acc.w * il + bv.w + xv.w;
        *reinterpret_cast<float4*>(&out[(size_t)n * 32 + c4]) = o;
    }
}

// ---------------------------------------------------------------- launch
extern "C" void kernel_launch(void* const* d_in, const int* in_sizes, int n_in,
                              void* d_out, int out_size, void* d_ws, size_t ws_size,
                              hipStream_t stream) {
    const float* x      = (const float*)d_in[0];
    const int*   eidx   = (const int*)  d_in[1];
    const float* W1     = (const float*)d_in[2];
    const float* a_src1 = (const float*)d_in[3];
    const float* a_dst1 = (const float*)d_in[4];
    const float* b1     = (const float*)d_in[5];
    const float* bn1_g  = (const float*)d_in[6];
    const float* bn1_b  = (const float*)d_in[7];
    const float* bn1_m  = (const float*)d_in[8];
    const float* bn1_v  = (const float*)d_in[9];
    const float* W2     = (const float*)d_in[10];
    const float* a_src2 = (const float*)d_in[11];
    const float* a_dst2 = (const float*)d_in[12];
    const float* b2     = (const float*)d_in[13];
    const float* bn2_g  = (const float*)d_in[14];
    const float* bn2_b  = (const float*)d_in[15];
    const float* bn2_m  = (const float*)d_in[16];
    const float* bn2_v  = (const float*)d_in[17];
    const float* W3     = (const float*)d_in[18];
    const float* a_src3 = (const float*)d_in[19];
    const float* a_dst3 = (const float*)d_in[20];
    const float* b3     = (const float*)d_in[21];
    const float* Ws1    = (const float*)d_in[22];
    const float* bs1    = (const float*)d_in[23];
    const float* Ws2    = (const float*)d_in[24];
    const float* bs2    = (const float*)d_in[25];

    const int N = in_sizes[0] / 128;   // 50000
    const int E = in_sizes[1] / 2;     // 800000
    const int Etot = E + N;
    const int* srcl = eidx;
    const int* dstl = eidx + E;

    char* ws = (char*)d_ws;
    size_t off = 0;
    auto alloc = [&](size_t bytes) -> void* {
        void* p = ws + off;
        off += (bytes + 255) & ~(size_t)255;
        return p;
    };
    unsigned short* xb    = (unsigned short*)alloc((size_t)N * 128 * 2);
    float*          feat  = (float*)alloc((size_t)N * 256 * 4);          // x0 skip (fp32)
    unsigned short* hbuf  = (unsigned short*)alloc((size_t)N * 256 * 2); // gemm h output
    unsigned short* h2b   = (unsigned short*)alloc((size_t)N * 256 * 2); // layer-1 agg out
    unsigned short* featb = (unsigned short*)alloc((size_t)N * 256 * 2); // layer-2 agg out
    float*          xsbuf = (float*)alloc((size_t)N * 32 * 4);
    unsigned short* h3b   = (unsigned short*)alloc((size_t)N * 32 * 2);
    float*          asb   = (float*)alloc((size_t)N * 8 * 4);
    float*          adb   = (float*)alloc((size_t)N * 8 * 4);
    unsigned short* Ws1t  = (unsigned short*)alloc((size_t)128 * 256 * 2);
    unsigned short* W1t   = (unsigned short*)alloc((size_t)128 * 256 * 2);
    unsigned short* Ws2t  = (unsigned short*)alloc((size_t)256 * 32 * 2);
    unsigned short* W2t   = (unsigned short*)alloc((size_t)256 * 256 * 2);
    unsigned short* W3t   = (unsigned short*)alloc((size_t)256 * 32 * 2);
    int* counts = (int*)alloc((size_t)N * 4);
    int* cursor = (int*)alloc((size_t)N * 4);
    int* indptr = (int*)alloc((size_t)(N + 1) * 4);
    int* bsums  = (int*)alloc(256 * 4);
    int* esrc   = (int*)alloc((size_t)Etot * 4);
    (void)ws_size; (void)n_in; (void)out_size;

    // ---- CSR by dst
    hipMemsetAsync(counts, 0, (size_t)N * 4, stream);
    int ceb = (Etot + 255) / 256;
    int nb  = (N + 255) / 256;
    count_kernel<<<ceb, 256, 0, stream>>>(dstl, E, N, counts);
    scan1<<<nb, 256, 0, stream>>>(counts, cursor, bsums, N);
    scan2<<<1, 256, 0, stream>>>(bsums, nb);
    scan3<<<nb, 256, 0, stream>>>(cursor, bsums, counts, indptr, cursor, N);
    fill_kernel<<<ceb, 256, 0, stream>>>(srcl, dstl, E, N, cursor, esrc);

    // ---- convert inputs
    f32_to_bf16<<<((N * 128 / 4) + 255) / 256, 256, 0, stream>>>(x, xb, N * 128 / 4);
    transpose_bf16<<<(128 * 256 + 255) / 256, 256, 0, stream>>>(Ws1, Ws1t, 128, 256);
    transpose_bf16<<<(128 * 256 + 255) / 256, 256, 0, stream>>>(W1, W1t, 128, 256);
    transpose_bf16<<<(256 * 32 + 255) / 256, 256, 0, stream>>>(Ws2, Ws2t, 256, 32);
    transpose_bf16<<<(256 * 256 + 255) / 256, 256, 0, stream>>>(W2, W2t, 256, 256);
    transpose_bf16<<<(256 * 32 + 255) / 256, 256, 0, stream>>>(W3, W3t, 256, 32);

    int gy = (N + 63) / 64;
    int gn4 = (N + 3) / 4;

    // ---- layer 1
    gemm_bf16<256, float><<<dim3(1, gy), 256, 0, stream>>>(xb, Ws1t, bs1, feat, N, 128, 256);
    gemm_bf16<256, unsigned short><<<dim3(1, gy), 256, 0, stream>>>(xb, W1t, nullptr, hbuf, N, 128, 256);
    alpha256<<<gn4, 256, 0, stream>>>(hbuf, a_src1, a_dst1, asb, adb, N);
    agg256<1><<<gn4, 256, 0, stream>>>(hbuf, asb, adb, indptr, esrc, b1,
                                       bn1_g, bn1_b, bn1_m, bn1_v, feat, h2b, N);

    // ---- layer 2
    gemm_bf16<32, float><<<dim3(1, gy), 256, 0, stream>>>(h2b, Ws2t, bs2, xsbuf, N, 256, 32);
    gemm_bf16<256, unsigned short><<<dim3(1, gy), 256, 0, stream>>>(h2b, W2t, nullptr, hbuf, N, 256, 256);
    alpha256<<<gn4, 256, 0, stream>>>(hbuf, a_src2, a_dst2, asb, adb, N);
    agg256<0><<<gn4, 256, 0, stream>>>(hbuf, asb, adb, indptr, esrc, b2,
                                       bn2_g, bn2_b, bn2_m, bn2_v, nullptr, featb, N);

    // ---- layer 3
    gemm_bf16<32, unsigned short><<<dim3(1, gy), 256, 0, stream>>>(featb, W3t, nullptr, h3b, N, 256, 32);
    alpha32<<<(N + 31) / 32, 256, 0, stream>>>(h3b, a_src3, a_dst3, asb, adb, N);
    agg32<<<gn4, 256, 0, stream>>>(h3b, asb, adb, indptr, esrc, b3, xsbuf,
                                   (float*)d_out, N);
}

// Round 5
// 626.894 us; speedup vs baseline: 1.1277x; 1.1277x over previous
//
#include <hip/hip_runtime.h>
#include <hip/hip_bf16.h>

#define NEG_SLOPE 0.2f
#define BN_EPS 1e-5f

typedef __attribute__((ext_vector_type(8))) short bf16x8;
typedef __attribute__((ext_vector_type(4))) float f32x4;
typedef __attribute__((ext_vector_type(8))) unsigned short u16x8;

__device__ __forceinline__ float bf2f(unsigned short u) {
    union { unsigned int i; float f; } x;
    x.i = ((unsigned int)u) << 16;
    return x.f;
}
__device__ __forceinline__ unsigned short f2bf(float f) {
    __hip_bfloat16 b = __float2bfloat16(f);
    return *reinterpret_cast<unsigned short*>(&b);
}
__device__ __forceinline__ float lrelu(float v) {
    return v > 0.f ? v : NEG_SLOPE * v;
}

// ---------------------------------------------------------------- CSR build
__global__ __launch_bounds__(256) void count_kernel(const int* __restrict__ dstl,
                                                    int E, int N, int* __restrict__ counts) {
    int i = blockIdx.x * 256 + threadIdx.x;
    if (i < E + N) {
        int d = (i < E) ? dstl[i] : (i - E);
        atomicAdd(&counts[d], 1);
    }
}

__device__ __forceinline__ int block_scan_incl(int v, int t) {
    int lane = t & 63, w = t >> 6;
    int sv = v;
    #pragma unroll
    for (int off = 1; off < 64; off <<= 1) {
        int u = __shfl_up(sv, off);
        if (lane >= off) sv += u;
    }
    __shared__ int ws[4];
    if (lane == 63) ws[w] = sv;
    __syncthreads();
    if (t == 0) {
        int a = 0;
        #pragma unroll
        for (int k = 0; k < 4; k++) { int x = ws[k]; ws[k] = a; a += x; }
    }
    __syncthreads();
    return sv + ws[w];
}

__global__ __launch_bounds__(256) void scan1(const int* __restrict__ counts,
                                             int* __restrict__ tmp,
                                             int* __restrict__ bsums, int n) {
    int t = threadIdx.x, i = blockIdx.x * 256 + t;
    int v = (i < n) ? counts[i] : 0;
    int incl = block_scan_incl(v, t);
    if (i < n) tmp[i] = incl;
    if (t == 255) bsums[blockIdx.x] = incl;
}

__global__ __launch_bounds__(256) void scan2(int* __restrict__ bsums, int nb) {
    int t = threadIdx.x;
    int v = (t < nb) ? bsums[t] : 0;
    int incl = block_scan_incl(v, t);
    if (t < nb) bsums[t] = incl - v;
}

__global__ __launch_bounds__(256) void scan3(const int* __restrict__ tmp,
                                             const int* __restrict__ bsums,
                                             const int* __restrict__ counts,
                                             int* __restrict__ indptr,
                                             int* __restrict__ cursor, int n) {
    int i = blockIdx.x * 256 + threadIdx.x;
    if (i < n) {
        int incl = tmp[i] + bsums[i >> 8];
        indptr[i + 1] = incl;
        cursor[i] = incl - counts[i];
        if (i == 0) indptr[0] = 0;
    }
}

__global__ __launch_bounds__(256) void fill_kernel(const int* __restrict__ srcl,
                                                   const int* __restrict__ dstl,
                                                   int E, int N,
                                                   int* __restrict__ cursor,
                                                   int* __restrict__ esrc) {
    int i = blockIdx.x * 256 + threadIdx.x;
    if (i < E + N) {
        int s, d;
        if (i < E) { s = srcl[i]; d = dstl[i]; }
        else       { s = d = i - E; }
        int slot = atomicAdd(&cursor[d], 1);
        esrc[slot] = s;
    }
}

// ---------------------------------------------------------------- converts
__global__ __launch_bounds__(256) void f32_to_bf16(const float* __restrict__ src,
                                                   unsigned short* __restrict__ dst, int n4) {
    int i = blockIdx.x * 256 + threadIdx.x;
    if (i < n4) {
        float4 v = reinterpret_cast<const float4*>(src)[i];
        ushort4 o;
        o.x = f2bf(v.x); o.y = f2bf(v.y); o.z = f2bf(v.z); o.w = f2bf(v.w);
        reinterpret_cast<ushort4*>(dst)[i] = o;
    }
}

// W[K x M] fp32 -> Wt[M x K] bf16
__global__ __launch_bounds__(256) void transpose_bf16(const float* __restrict__ src,
                                                      unsigned short* __restrict__ dst,
                                                      int K, int M) {
    int i = blockIdx.x * 256 + threadIdx.x;
    if (i < K * M) {
        int m = i / K, k = i - m * K;
        dst[i] = f2bf(src[(size_t)k * M + m]);
    }
}

// ---------------------------------------------------------------- bf16 MFMA GEMM
// C[M x NC] = A[M x K](bf16) @ B, Bt[NC x K](bf16) = B^T. Block: 64 rows x NCT cols.
// NCT == NC => A fetched exactly once; B tile stays L2-resident.
template <int NCT, typename OutT>
__global__ __launch_bounds__(256) void gemm_bf16(const unsigned short* __restrict__ A,
                                                 const unsigned short* __restrict__ Bt,
                                                 const float* __restrict__ bias,
                                                 OutT* __restrict__ C,
                                                 int M, int K, int NC) {
    constexpr int NF = NCT / 16;
    int t = threadIdx.x;
    int w = t >> 6, lane = t & 63;
    int l16 = lane & 15, quad = lane >> 4;
    int rowBase = blockIdx.y * 64 + w * 16;
    int colBase = blockIdx.x * NCT;

    f32x4 acc[NF];
    #pragma unroll
    for (int f = 0; f < NF; f++) acc[f] = (f32x4){0.f, 0.f, 0.f, 0.f};

    int arow = rowBase + l16;
    if (arow >= M) arow = M - 1;
    const unsigned short* aptr = A + (size_t)arow * K + quad * 8;

    for (int k0 = 0; k0 < K; k0 += 32) {
        bf16x8 af = *reinterpret_cast<const bf16x8*>(aptr + k0);
        #pragma unroll
        for (int f = 0; f < NF; f++) {
            int col = colBase + f * 16 + l16;
            bf16x8 bf = *reinterpret_cast<const bf16x8*>(&Bt[(size_t)col * K + k0 + quad * 8]);
            acc[f] = __builtin_amdgcn_mfma_f32_16x16x32_bf16(af, bf, acc[f], 0, 0, 0);
        }
    }

    #pragma unroll
    for (int f = 0; f < NF; f++) {
        int col = colBase + f * 16 + l16;
        float bv = bias ? bias[col] : 0.f;
        #pragma unroll
        for (int r = 0; r < 4; r++) {
            int row = rowBase + quad * 4 + r;
            if (row < M) {
                float v = acc[f][r] + bv;
                if constexpr (sizeof(OutT) == 2) C[(size_t)row * NC + col] = (OutT)f2bf(v);
                else                             C[(size_t)row * NC + col] = v;
            }
        }
    }
}

// ---------------------------------------------------------------- alpha (H=8,C=32), wave/node
__global__ __launch_bounds__(256) void alpha256(const unsigned short* __restrict__ h,
                                                const float* __restrict__ a_s,
                                                const float* __restrict__ a_d,
                                                float* __restrict__ as_out,
                                                float* __restrict__ ad_out, int N) {
    int t = threadIdx.x;
    int n = blockIdx.x * 4 + (t >> 6);
    if (n >= N) return;
    int lane = t & 63, lane4 = lane * 4;
    ushort4 hv = *reinterpret_cast<const ushort4*>(&h[(size_t)n * 256 + lane4]);
    float4 sv = *reinterpret_cast<const float4*>(&a_s[lane4]);
    float4 dv = *reinterpret_cast<const float4*>(&a_d[lane4]);
    float h0 = bf2f(hv.x), h1 = bf2f(hv.y), h2 = bf2f(hv.z), h3 = bf2f(hv.w);
    float va = h0 * sv.x + h1 * sv.y + h2 * sv.z + h3 * sv.w;
    float vd = h0 * dv.x + h1 * dv.y + h2 * dv.z + h3 * dv.w;
    #pragma unroll
    for (int off = 1; off < 8; off <<= 1) {
        va += __shfl_xor(va, off);
        vd += __shfl_xor(vd, off);
    }
    if ((lane & 7) == 0) {
        as_out[n * 8 + (lane >> 3)] = va;
        ad_out[n * 8 + (lane >> 3)] = vd;
    }
}

// ---------------------------------------------------------------- alpha (H=1,C=32), 8 nodes/wave
__global__ __launch_bounds__(256) void alpha32(const unsigned short* __restrict__ h,
                                               const float* __restrict__ a_s,
                                               const float* __restrict__ a_d,
                                               float* __restrict__ as_out,
                                               float* __restrict__ ad_out, int N) {
    int t = threadIdx.x;
    int lane = t & 63;
    int n = blockIdx.x * 32 + (t >> 6) * 8 + (lane >> 3);
    int c4 = (lane & 7) * 4;
    if (n >= N) return;
    ushort4 hv = *reinterpret_cast<const ushort4*>(&h[(size_t)n * 32 + c4]);
    float4 sv = *reinterpret_cast<const float4*>(&a_s[c4]);
    float4 dv = *reinterpret_cast<const float4*>(&a_d[c4]);
    float h0 = bf2f(hv.x), h1 = bf2f(hv.y), h2 = bf2f(hv.z), h3 = bf2f(hv.w);
    float va = h0 * sv.x + h1 * sv.y + h2 * sv.z + h3 * sv.w;
    float vd = h0 * dv.x + h1 * dv.y + h2 * dv.z + h3 * dv.w;
    #pragma unroll
    for (int off = 1; off < 8; off <<= 1) {
        va += __shfl_xor(va, off);
        vd += __shfl_xor(vd, off);
    }
    if ((lane & 7) == 0) {
        as_out[n] = va;
        ad_out[n] = vd;
    }
}

// ---------------------------------------------------------------- aggregation H=8,C=32
// One wave per node, SINGLE pass (no max-shift), 8 edges / 4KB in flight.
// Weight lanes: lane = e_sub*8 + h_sub; gather: lane owns channels lane*4..+3.
// R4 lesson: keep per-lane arrays <= 8x ushort4 to stay at VGPR~44, no spill.
template <int MODE>
__global__ __launch_bounds__(256) void agg256(const unsigned short* __restrict__ hfeat,
                                              const float* __restrict__ as,
                                              const float* __restrict__ ad,
                                              const int* __restrict__ indptr,
                                              const int* __restrict__ esrc,
                                              const float* __restrict__ bias,
                                              const float* __restrict__ bn_g,
                                              const float* __restrict__ bn_b,
                                              const float* __restrict__ bn_m,
                                              const float* __restrict__ bn_v,
                                              const float* __restrict__ skip,
                                              unsigned short* __restrict__ out, int N) {
    int t = threadIdx.x;
    int n = blockIdx.x * 4 + (t >> 6);
    if (n >= N) return;
    int lane = t & 63;
    int e_sub = lane >> 3, h_sub = lane & 7;
    int ch_head = lane >> 3;           // head owning channels lane*4..+3
    int lane4 = lane * 4;
    int start = indptr[n], end = indptr[n + 1];
    int cnt = end - start;

    float adh = ad[n * 8 + h_sub];

    float4 acc = make_float4(0.f, 0.f, 0.f, 0.f);
    float sm = 0.f;
    int nfull = cnt & ~7;
    int i0 = start;
    for (; i0 < start + nfull; i0 += 8) {
        int s_l = esrc[i0 + e_sub];
        float w8 = __expf(lrelu(as[s_l * 8 + h_sub] + adh));
        sm += w8;
        int se[8]; float we[8];
        #pragma unroll
        for (int e = 0; e < 8; e++) {
            se[e] = __shfl(s_l, e * 8);
            we[e] = __shfl(w8, e * 8 + ch_head);
        }
        ushort4 hv[8];
        #pragma unroll
        for (int e = 0; e < 8; e++)
            hv[e] = *reinterpret_cast<const ushort4*>(&hfeat[(size_t)se[e] * 256 + lane4]);
        #pragma unroll
        for (int e = 0; e < 8; e++) {
            acc.x = fmaf(we[e], bf2f(hv[e].x), acc.x);
            acc.y = fmaf(we[e], bf2f(hv[e].y), acc.y);
            acc.z = fmaf(we[e], bf2f(hv[e].z), acc.z);
            acc.w = fmaf(we[e], bf2f(hv[e].w), acc.w);
        }
    }
    int rem = cnt - nfull;
    if (rem) {
        int idx = i0 + e_sub;
        int s_l = esrc[idx < end ? idx : end - 1];
        float w8 = (idx < end) ? __expf(lrelu(as[s_l * 8 + h_sub] + adh)) : 0.f;
        sm += w8;
        #pragma unroll
        for (int e = 0; e < 8; e++) {
            if (e < rem) {
                int se = __shfl(s_l, e * 8);
                float we = __shfl(w8, e * 8 + ch_head);
                ushort4 hv = *reinterpret_cast<const ushort4*>(&hfeat[(size_t)se * 256 + lane4]);
                acc.x = fmaf(we, bf2f(hv.x), acc.x);
                acc.y = fmaf(we, bf2f(hv.y), acc.y);
                acc.z = fmaf(we, bf2f(hv.z), acc.z);
                acc.w = fmaf(we, bf2f(hv.w), acc.w);
            }
        }
    }
    #pragma unroll
    for (int off = 8; off < 64; off <<= 1) sm += __shfl_xor(sm, off);
    float il = 1.f / (sm + 1e-16f);
    float il_c = __shfl(il, ch_head);

    // ---- epilogue
    float4 bv  = *reinterpret_cast<const float4*>(&bias[lane4]);
    float4 gv  = *reinterpret_cast<const float4*>(&bn_g[lane4]);
    float4 bbv = *reinterpret_cast<const float4*>(&bn_b[lane4]);
    float4 mv  = *reinterpret_cast<const float4*>(&bn_m[lane4]);
    float4 vv  = *reinterpret_cast<const float4*>(&bn_v[lane4]);
    float o[4] = {acc.x * il_c + bv.x, acc.y * il_c + bv.y,
                  acc.z * il_c + bv.z, acc.w * il_c + bv.w};
    float g[4] = {gv.x, gv.y, gv.z, gv.w}, bb[4] = {bbv.x, bbv.y, bbv.z, bbv.w};
    float m[4] = {mv.x, mv.y, mv.z, mv.w}, vr[4] = {vv.x, vv.y, vv.z, vv.w};
    float sk[4] = {0.f, 0.f, 0.f, 0.f};
    if (MODE == 1) {
        float4 s4 = *reinterpret_cast<const float4*>(&skip[(size_t)n * 256 + lane4]);
        sk[0] = s4.x; sk[1] = s4.y; sk[2] = s4.z; sk[3] = s4.w;
    }
    ushort4 res;
    unsigned short* rp = &res.x;
    #pragma unroll
    for (int j = 0; j < 4; j++) {
        float val = (o[j] - m[j]) * rsqrtf(vr[j] + BN_EPS) * g[j] + bb[j];
        val = val > 0.f ? val : (__expf(val) - 1.f);
        val += sk[j];
        rp[j] = f2bf(val);
    }
    *reinterpret_cast<ushort4*>(&out[(size_t)n * 256 + lane4]) = res;
}

// ---------------------------------------------------------------- aggregation H=1,C=32
// One wave per node; lane = e_sub*8 + c_sub; single pass, 16 edges in flight.
__global__ __launch_bounds__(256) void agg32(const unsigned short* __restrict__ h3,
                                             const float* __restrict__ as,
                                             const float* __restrict__ ad,
                                             const int* __restrict__ indptr,
                                             const int* __restrict__ esrc,
                                             const float* __restrict__ b3,
                                             const float* __restrict__ xs,
                                             float* __restrict__ out, int N) {
    int t = threadIdx.x;
    int n = blockIdx.x * 4 + (t >> 6);
    if (n >= N) return;
    int lane = t & 63;
    int e_sub = lane >> 3, c4 = (lane & 7) * 4;
    int start = indptr[n], end = indptr[n + 1];
    float adn = ad[n];

    float4 acc = make_float4(0.f, 0.f, 0.f, 0.f);
    float sm = 0.f;
    int i0 = start;
    for (; i0 + 16 <= end; i0 += 16) {
        int sA = esrc[i0 + e_sub];
        int sB = esrc[i0 + 8 + e_sub];
        float wA = __expf(lrelu(as[sA] + adn));
        float wB = __expf(lrelu(as[sB] + adn));
        sm += wA + wB;
        ushort4 hA = *reinterpret_cast<const ushort4*>(&h3[(size_t)sA * 32 + c4]);
        ushort4 hB = *reinterpret_cast<const ushort4*>(&h3[(size_t)sB * 32 + c4]);
        acc.x = fmaf(wA, bf2f(hA.x), acc.x); acc.y = fmaf(wA, bf2f(hA.y), acc.y);
        acc.z = fmaf(wA, bf2f(hA.z), acc.z); acc.w = fmaf(wA, bf2f(hA.w), acc.w);
        acc.x = fmaf(wB, bf2f(hB.x), acc.x); acc.y = fmaf(wB, bf2f(hB.y), acc.y);
        acc.z = fmaf(wB, bf2f(hB.z), acc.z); acc.w = fmaf(wB, bf2f(hB.w), acc.w);
    }
    for (; i0 < end; i0 += 8) {
        int idx = i0 + e_sub;
        bool valid = idx < end;
        if (valid) {
            int s = esrc[idx];
            float w = __expf(lrelu(as[s] + adn));
            sm += w;
            ushort4 hv = *reinterpret_cast<const ushort4*>(&h3[(size_t)s * 32 + c4]);
            acc.x = fmaf(w, bf2f(hv.x), acc.x);
            acc.y = fmaf(w, bf2f(hv.y), acc.y);
            acc.z = fmaf(w, bf2f(hv.z), acc.z);
            acc.w = fmaf(w, bf2f(hv.w), acc.w);
        }
    }
    #pragma unroll
    for (int off = 8; off < 64; off <<= 1) {
        sm    += __shfl_xor(sm, off);
        acc.x += __shfl_xor(acc.x, off);
        acc.y += __shfl_xor(acc.y, off);
        acc.z += __shfl_xor(acc.z, off);
        acc.w += __shfl_xor(acc.w, off);
    }
    if (e_sub == 0) {
        float il = 1.f / (sm + 1e-16f);
        float4 bv = *reinterpret_cast<const float4*>(&b3[c4]);
        float4 xv = *reinterpret_cast<const float4*>(&xs[(size_t)n * 32 + c4]);
        float4 o;
        o.x = acc.x * il + bv.x + xv.x;
        o.y = acc.y * il + bv.y + xv.y;
        o.z = acc.z * il + bv.z + xv.z;
        o.w = acc.w * il + bv.w + xv.w;
        *reinterpret_cast<float4*>(&out[(size_t)n * 32 + c4]) = o;
    }
}

// ---------------------------------------------------------------- launch
extern "C" void kernel_launch(void* const* d_in, const int* in_sizes, int n_in,
                              void* d_out, int out_size, void* d_ws, size_t ws_size,
                              hipStream_t stream) {
    const float* x      = (const float*)d_in[0];
    const int*   eidx   = (const int*)  d_in[1];
    const float* W1     = (const float*)d_in[2];
    const float* a_src1 = (const float*)d_in[3];
    const float* a_dst1 = (const float*)d_in[4];
    const float* b1     = (const float*)d_in[5];
    const float* bn1_g  = (const float*)d_in[6];
    const float* bn1_b  = (const float*)d_in[7];
    const float* bn1_m  = (const float*)d_in[8];
    const float* bn1_v  = (const float*)d_in[9];
    const float* W2     = (const float*)d_in[10];
    const float* a_src2 = (const float*)d_in[11];
    const float* a_dst2 = (const float*)d_in[12];
    const float* b2     = (const float*)d_in[13];
    const float* bn2_g  = (const float*)d_in[14];
    const float* bn2_b  = (const float*)d_in[15];
    const float* bn2_m  = (const float*)d_in[16];
    const float* bn2_v  = (const float*)d_in[17];
    const float* W3     = (const float*)d_in[18];
    const float* a_src3 = (const float*)d_in[19];
    const float* a_dst3 = (const float*)d_in[20];
    const float* b3     = (const float*)d_in[21];
    const float* Ws1    = (const float*)d_in[22];
    const float* bs1    = (const float*)d_in[23];
    const float* Ws2    = (const float*)d_in[24];
    const float* bs2    = (const float*)d_in[25];

    const int N = in_sizes[0] / 128;   // 50000
    const int E = in_sizes[1] / 2;     // 800000
    const int Etot = E + N;
    const int* srcl = eidx;
    const int* dstl = eidx + E;

    char* ws = (char*)d_ws;
    size_t off = 0;
    auto alloc = [&](size_t bytes) -> void* {
        void* p = ws + off;
        off += (bytes + 255) & ~(size_t)255;
        return p;
    };
    unsigned short* xb    = (unsigned short*)alloc((size_t)N * 128 * 2);
    float*          feat  = (float*)alloc((size_t)N * 256 * 4);          // x0 skip (fp32)
    unsigned short* hbuf  = (unsigned short*)alloc((size_t)N * 256 * 2); // gemm h output
    unsigned short* h2b   = (unsigned short*)alloc((size_t)N * 256 * 2); // layer-1 agg out
    unsigned short* featb = (unsigned short*)alloc((size_t)N * 256 * 2); // layer-2 agg out
    float*          xsbuf = (float*)alloc((size_t)N * 32 * 4);
    unsigned short* h3b   = (unsigned short*)alloc((size_t)N * 32 * 2);
    float*          asb   = (float*)alloc((size_t)N * 8 * 4);
    float*          adb   = (float*)alloc((size_t)N * 8 * 4);
    unsigned short* Ws1t  = (unsigned short*)alloc((size_t)128 * 256 * 2);
    unsigned short* W1t   = (unsigned short*)alloc((size_t)128 * 256 * 2);
    unsigned short* Ws2t  = (unsigned short*)alloc((size_t)256 * 32 * 2);
    unsigned short* W2t   = (unsigned short*)alloc((size_t)256 * 256 * 2);
    unsigned short* W3t   = (unsigned short*)alloc((size_t)256 * 32 * 2);
    int* counts = (int*)alloc((size_t)N * 4);
    int* cursor = (int*)alloc((size_t)N * 4);
    int* indptr = (int*)alloc((size_t)(N + 1) * 4);
    int* bsums  = (int*)alloc(256 * 4);
    int* esrc   = (int*)alloc((size_t)Etot * 4);
    (void)ws_size; (void)n_in; (void)out_size;

    // ---- CSR by dst
    hipMemsetAsync(counts, 0, (size_t)N * 4, stream);
    int ceb = (Etot + 255) / 256;
    int nb  = (N + 255) / 256;
    count_kernel<<<ceb, 256, 0, stream>>>(dstl, E, N, counts);
    scan1<<<nb, 256, 0, stream>>>(counts, cursor, bsums, N);
    scan2<<<1, 256, 0, stream>>>(bsums, nb);
    scan3<<<nb, 256, 0, stream>>>(cursor, bsums, counts, indptr, cursor, N);
    fill_kernel<<<ceb, 256, 0, stream>>>(srcl, dstl, E, N, cursor, esrc);

    // ---- convert inputs
    f32_to_bf16<<<((N * 128 / 4) + 255) / 256, 256, 0, stream>>>(x, xb, N * 128 / 4);
    transpose_bf16<<<(128 * 256 + 255) / 256, 256, 0, stream>>>(Ws1, Ws1t, 128, 256);
    transpose_bf16<<<(128 * 256 + 255) / 256, 256, 0, stream>>>(W1, W1t, 128, 256);
    transpose_bf16<<<(256 * 32 + 255) / 256, 256, 0, stream>>>(Ws2, Ws2t, 256, 32);
    transpose_bf16<<<(256 * 256 + 255) / 256, 256, 0, stream>>>(W2, W2t, 256, 256);
    transpose_bf16<<<(256 * 32 + 255) / 256, 256, 0, stream>>>(W3, W3t, 256, 32);

    int gy = (N + 63) / 64;
    int gn4 = (N + 3) / 4;

    // ---- layer 1
    gemm_bf16<256, float><<<dim3(1, gy), 256, 0, stream>>>(xb, Ws1t, bs1, feat, N, 128, 256);
    gemm_bf16<256, unsigned short><<<dim3(1, gy), 256, 0, stream>>>(xb, W1t, nullptr, hbuf, N, 128, 256);
    alpha256<<<gn4, 256, 0, stream>>>(hbuf, a_src1, a_dst1, asb, adb, N);
    agg256<1><<<gn4, 256, 0, stream>>>(hbuf, asb, adb, indptr, esrc, b1,
                                       bn1_g, bn1_b, bn1_m, bn1_v, feat, h2b, N);

    // ---- layer 2
    gemm_bf16<32, float><<<dim3(1, gy), 256, 0, stream>>>(h2b, Ws2t, bs2, xsbuf, N, 256, 32);
    gemm_bf16<256, unsigned short><<<dim3(1, gy), 256, 0, stream>>>(h2b, W2t, nullptr, hbuf, N, 256, 256);
    alpha256<<<gn4, 256, 0, stream>>>(hbuf, a_src2, a_dst2, asb, adb, N);
    agg256<0><<<gn4, 256, 0, stream>>>(hbuf, asb, adb, indptr, esrc, b2,
                                       bn2_g, bn2_b, bn2_m, bn2_v, nullptr, featb, N);

    // ---- layer 3
    gemm_bf16<32, unsigned short><<<dim3(1, gy), 256, 0, stream>>>(featb, W3t, nullptr, h3b, N, 256, 32);
    alpha32<<<(N + 31) / 32, 256, 0, stream>>>(h3b, a_src3, a_dst3, asb, adb, N);
    agg32<<<gn4, 256, 0, stream>>>(h3b, asb, adb, indptr, esrc, b3, xsbuf,
                                   (float*)d_out, N);
}

// Round 6
// 514.665 us; speedup vs baseline: 1.3736x; 1.2181x over previous
//
#include <hip/hip_runtime.h>
#include <hip/hip_bf16.h>

#define NEG_SLOPE 0.2f
#define BN_EPS 1e-5f

typedef __attribute__((ext_vector_type(8))) short bf16x8;
typedef __attribute__((ext_vector_type(4))) float f32x4;

__device__ __forceinline__ float bf2f(unsigned short u) {
    union { unsigned int i; float f; } x;
    x.i = ((unsigned int)u) << 16;
    return x.f;
}
__device__ __forceinline__ unsigned short f2bf(float f) {
    __hip_bfloat16 b = __float2bfloat16(f);
    return *reinterpret_cast<unsigned short*>(&b);
}
__device__ __forceinline__ float lrelu(float v) {
    return v > 0.f ? v : NEG_SLOPE * v;
}
__device__ __forceinline__ void gload_lds16(const void* g, void* l) {
    __builtin_amdgcn_global_load_lds(
        (const __attribute__((address_space(1))) unsigned int*)(g),
        (__attribute__((address_space(3))) unsigned int*)(l),
        16, 0, 0);
}

// ---------------------------------------------------------------- CSR build
__global__ __launch_bounds__(256) void count_kernel(const int* __restrict__ dstl,
                                                    int E, int N, int* __restrict__ counts) {
    int i = blockIdx.x * 256 + threadIdx.x;
    if (i < E + N) {
        int d = (i < E) ? dstl[i] : (i - E);
        atomicAdd(&counts[d], 1);
    }
}

__device__ __forceinline__ int block_scan_incl(int v, int t) {
    int lane = t & 63, w = t >> 6;
    int sv = v;
    #pragma unroll
    for (int off = 1; off < 64; off <<= 1) {
        int u = __shfl_up(sv, off);
        if (lane >= off) sv += u;
    }
    __shared__ int ws[4];
    if (lane == 63) ws[w] = sv;
    __syncthreads();
    if (t == 0) {
        int a = 0;
        #pragma unroll
        for (int k = 0; k < 4; k++) { int x = ws[k]; ws[k] = a; a += x; }
    }
    __syncthreads();
    return sv + ws[w];
}

__global__ __launch_bounds__(256) void scan1(const int* __restrict__ counts,
                                             int* __restrict__ tmp,
                                             int* __restrict__ bsums, int n) {
    int t = threadIdx.x, i = blockIdx.x * 256 + t;
    int v = (i < n) ? counts[i] : 0;
    int incl = block_scan_incl(v, t);
    if (i < n) tmp[i] = incl;
    if (t == 255) bsums[blockIdx.x] = incl;
}

__global__ __launch_bounds__(256) void scan2(int* __restrict__ bsums, int nb) {
    int t = threadIdx.x;
    int v = (t < nb) ? bsums[t] : 0;
    int incl = block_scan_incl(v, t);
    if (t < nb) bsums[t] = incl - v;
}

__global__ __launch_bounds__(256) void scan3(const int* __restrict__ tmp,
                                             const int* __restrict__ bsums,
                                             const int* __restrict__ counts,
                                             int* __restrict__ indptr,
                                             int* __restrict__ cursor, int n) {
    int i = blockIdx.x * 256 + threadIdx.x;
    if (i < n) {
        int incl = tmp[i] + bsums[i >> 8];
        indptr[i + 1] = incl;
        cursor[i] = incl - counts[i];
        if (i == 0) indptr[0] = 0;
    }
}

__global__ __launch_bounds__(256) void fill_kernel(const int* __restrict__ srcl,
                                                   const int* __restrict__ dstl,
                                                   int E, int N,
                                                   int* __restrict__ cursor,
                                                   int* __restrict__ esrc) {
    int i = blockIdx.x * 256 + threadIdx.x;
    if (i < E + N) {
        int s, d;
        if (i < E) { s = srcl[i]; d = dstl[i]; }
        else       { s = d = i - E; }
        int slot = atomicAdd(&cursor[d], 1);
        esrc[slot] = s;
    }
}

// ---------------------------------------------------------------- converts
__global__ __launch_bounds__(256) void f32_to_bf16(const float* __restrict__ src,
                                                   unsigned short* __restrict__ dst, int n4) {
    int i = blockIdx.x * 256 + threadIdx.x;
    if (i < n4) {
        float4 v = reinterpret_cast<const float4*>(src)[i];
        ushort4 o;
        o.x = f2bf(v.x); o.y = f2bf(v.y); o.z = f2bf(v.z); o.w = f2bf(v.w);
        reinterpret_cast<ushort4*>(dst)[i] = o;
    }
}

// W[K x M] fp32 -> Wt[M x K] bf16
__global__ __launch_bounds__(256) void transpose_bf16(const float* __restrict__ src,
                                                      unsigned short* __restrict__ dst,
                                                      int K, int M) {
    int i = blockIdx.x * 256 + threadIdx.x;
    if (i < K * M) {
        int m = i / K, k = i - m * K;
        dst[i] = f2bf(src[(size_t)k * M + m]);
    }
}

// ---------------------------------------------------------------- tiled MFMA GEMM
// C[M x NCtot] = A[M x K](bf16) @ B, Bt[NCtot x K] = B^T (bf16).
// 128x128 tile, BK=32, double-buffered LDS via global_load_lds(16B).
// LDS layout per matrix: [chunk(4)][row(128)][16B] (chunk = 8 k-elems).
// Epilogue split: col < split -> bf16 to outBf (stride ldBf);
//                 col >= split -> fp32 to outF (stride ldF) + biasF[col-split].
__global__ __launch_bounds__(256) void gemm_tile(const unsigned short* __restrict__ A,
                                                 const unsigned short* __restrict__ Bt,
                                                 unsigned short* __restrict__ outBf,
                                                 float* __restrict__ outF,
                                                 const float* __restrict__ biasF,
                                                 int M, int K, int NCtot, int split,
                                                 int ldBf, int ldF) {
    __shared__ __align__(16) char smem[2][2][8192];
    int t = threadIdx.x;
    int w = t >> 6, lane = t & 63;
    int l16 = lane & 15, quad = lane >> 4;
    int warp_r = w >> 1, warp_c = w & 1;
    int rowBase = blockIdx.y * 128;
    int colBase = blockIdx.x * 128;

    // staging coords for this thread (row/col clamped; duplicate reads are fine)
    int row_l = t & 127;
    int jchunk = t >> 7;   // 0 or 1
    int arow_st = rowBase + row_l; if (arow_st >= M) arow_st = M - 1;
    int bcol_st = colBase + row_l; if (bcol_st >= NCtot) bcol_st = NCtot - 1;
    const unsigned short* aRow = A + (size_t)arow_st * K;
    const unsigned short* bRow = Bt + (size_t)bcol_st * K;

    f32x4 acc[4][4];
    #pragma unroll
    for (int i = 0; i < 4; i++)
        #pragma unroll
        for (int j = 0; j < 4; j++) acc[i][j] = (f32x4){0.f, 0.f, 0.f, 0.f};

    auto stage = [&](int buf, int k0) {
        #pragma unroll
        for (int j = 0; j < 2; j++) {
            int chunk = j * 2 + jchunk;
            gload_lds16(aRow + k0 + chunk * 8, &smem[buf][0][(size_t)j * 4096 + (size_t)t * 16]);
            gload_lds16(bRow + k0 + chunk * 8, &smem[buf][1][(size_t)j * 4096 + (size_t)t * 16]);
        }
    };

    stage(0, 0);
    __syncthreads();
    int niter = K >> 5;
    for (int it = 0; it < niter; ++it) {
        if (it + 1 < niter) stage((it + 1) & 1, (it + 1) << 5);
        const char* Ab = &smem[it & 1][0][0];
        const char* Bb = &smem[it & 1][1][0];
        bf16x8 a[4], b[4];
        #pragma unroll
        for (int i = 0; i < 4; i++)
            a[i] = *reinterpret_cast<const bf16x8*>(Ab + quad * 2048 + (warp_r * 64 + i * 16 + l16) * 16);
        #pragma unroll
        for (int j = 0; j < 4; j++)
            b[j] = *reinterpret_cast<const bf16x8*>(Bb + quad * 2048 + (warp_c * 64 + j * 16 + l16) * 16);
        #pragma unroll
        for (int i = 0; i < 4; i++)
            #pragma unroll
            for (int j = 0; j < 4; j++)
                acc[i][j] = __builtin_amdgcn_mfma_f32_16x16x32_bf16(a[i], b[j], acc[i][j], 0, 0, 0);
        __syncthreads();
    }

    #pragma unroll
    for (int i = 0; i < 4; i++) {
        #pragma unroll
        for (int r = 0; r < 4; r++) {
            int row = rowBase + warp_r * 64 + i * 16 + quad * 4 + r;
            if (row >= M) continue;
            #pragma unroll
            for (int j = 0; j < 4; j++) {
                int c = colBase + warp_c * 64 + j * 16 + l16;
                float v = acc[i][j][r];
                if (c < split) outBf[(size_t)row * ldBf + c] = f2bf(v);
                else           outF[(size_t)row * ldF + (c - split)] = v + biasF[c - split];
            }
        }
    }
}

// ---------------------------------------------------------------- register-direct GEMM (skinny NC=32)
template <int NCT, typename OutT>
__global__ __launch_bounds__(256) void gemm_bf16(const unsigned short* __restrict__ A,
                                                 const unsigned short* __restrict__ Bt,
                                                 const float* __restrict__ bias,
                                                 OutT* __restrict__ C,
                                                 int M, int K, int NC) {
    constexpr int NF = NCT / 16;
    int t = threadIdx.x;
    int w = t >> 6, lane = t & 63;
    int l16 = lane & 15, quad = lane >> 4;
    int rowBase = blockIdx.y * 64 + w * 16;
    int colBase = blockIdx.x * NCT;

    f32x4 acc[NF];
    #pragma unroll
    for (int f = 0; f < NF; f++) acc[f] = (f32x4){0.f, 0.f, 0.f, 0.f};

    int arow = rowBase + l16;
    if (arow >= M) arow = M - 1;
    const unsigned short* aptr = A + (size_t)arow * K + quad * 8;

    for (int k0 = 0; k0 < K; k0 += 32) {
        bf16x8 af = *reinterpret_cast<const bf16x8*>(aptr + k0);
        #pragma unroll
        for (int f = 0; f < NF; f++) {
            int col = colBase + f * 16 + l16;
            bf16x8 bf = *reinterpret_cast<const bf16x8*>(&Bt[(size_t)col * K + k0 + quad * 8]);
            acc[f] = __builtin_amdgcn_mfma_f32_16x16x32_bf16(af, bf, acc[f], 0, 0, 0);
        }
    }

    #pragma unroll
    for (int f = 0; f < NF; f++) {
        int col = colBase + f * 16 + l16;
        float bv = bias ? bias[col] : 0.f;
        #pragma unroll
        for (int r = 0; r < 4; r++) {
            int row = rowBase + quad * 4 + r;
            if (row < M) {
                float v = acc[f][r] + bv;
                if constexpr (sizeof(OutT) == 2) C[(size_t)row * NC + col] = (OutT)f2bf(v);
                else                             C[(size_t)row * NC + col] = v;
            }
        }
    }
}

// ---------------------------------------------------------------- alpha (H=8,C=32), wave/node
__global__ __launch_bounds__(256) void alpha256(const unsigned short* __restrict__ h,
                                                const float* __restrict__ a_s,
                                                const float* __restrict__ a_d,
                                                float* __restrict__ as_out,
                                                float* __restrict__ ad_out, int N) {
    int t = threadIdx.x;
    int n = blockIdx.x * 4 + (t >> 6);
    if (n >= N) return;
    int lane = t & 63, lane4 = lane * 4;
    ushort4 hv = *reinterpret_cast<const ushort4*>(&h[(size_t)n * 256 + lane4]);
    float4 sv = *reinterpret_cast<const float4*>(&a_s[lane4]);
    float4 dv = *reinterpret_cast<const float4*>(&a_d[lane4]);
    float h0 = bf2f(hv.x), h1 = bf2f(hv.y), h2 = bf2f(hv.z), h3 = bf2f(hv.w);
    float va = h0 * sv.x + h1 * sv.y + h2 * sv.z + h3 * sv.w;
    float vd = h0 * dv.x + h1 * dv.y + h2 * dv.z + h3 * dv.w;
    #pragma unroll
    for (int off = 1; off < 8; off <<= 1) {
        va += __shfl_xor(va, off);
        vd += __shfl_xor(vd, off);
    }
    if ((lane & 7) == 0) {
        as_out[n * 8 + (lane >> 3)] = va;
        ad_out[n * 8 + (lane >> 3)] = vd;
    }
}

// ---------------------------------------------------------------- alpha (H=1,C=32), 8 nodes/wave
__global__ __launch_bounds__(256) void alpha32(const unsigned short* __restrict__ h,
                                               const float* __restrict__ a_s,
                                               const float* __restrict__ a_d,
                                               float* __restrict__ as_out,
                                               float* __restrict__ ad_out, int N) {
    int t = threadIdx.x;
    int lane = t & 63;
    int n = blockIdx.x * 32 + (t >> 6) * 8 + (lane >> 3);
    int c4 = (lane & 7) * 4;
    if (n >= N) return;
    ushort4 hv = *reinterpret_cast<const ushort4*>(&h[(size_t)n * 32 + c4]);
    float4 sv = *reinterpret_cast<const float4*>(&a_s[c4]);
    float4 dv = *reinterpret_cast<const float4*>(&a_d[c4]);
    float h0 = bf2f(hv.x), h1 = bf2f(hv.y), h2 = bf2f(hv.z), h3 = bf2f(hv.w);
    float va = h0 * sv.x + h1 * sv.y + h2 * sv.z + h3 * sv.w;
    float vd = h0 * dv.x + h1 * dv.y + h2 * dv.z + h3 * dv.w;
    #pragma unroll
    for (int off = 1; off < 8; off <<= 1) {
        va += __shfl_xor(va, off);
        vd += __shfl_xor(vd, off);
    }
    if ((lane & 7) == 0) {
        as_out[n] = va;
        ad_out[n] = vd;
    }
}

// ---------------------------------------------------------------- aggregation H=8,C=32
// One wave per node, single pass (no max-shift), 8 edges / 4KB in flight, no LDS.
template <int MODE>
__global__ __launch_bounds__(256) void agg256(const unsigned short* __restrict__ hfeat,
                                              const float* __restrict__ as,
                                              const float* __restrict__ ad,
                                              const int* __restrict__ indptr,
                                              const int* __restrict__ esrc,
                                              const float* __restrict__ bias,
                                              const float* __restrict__ bn_g,
                                              const float* __restrict__ bn_b,
                                              const float* __restrict__ bn_m,
                                              const float* __restrict__ bn_v,
                                              const float* __restrict__ skip,
                                              unsigned short* __restrict__ out, int N) {
    int t = threadIdx.x;
    int n = blockIdx.x * 4 + (t >> 6);
    if (n >= N) return;
    int lane = t & 63;
    int e_sub = lane >> 3, h_sub = lane & 7;
    int ch_head = lane >> 3;
    int lane4 = lane * 4;
    int start = indptr[n], end = indptr[n + 1];
    int cnt = end - start;

    float adh = ad[n * 8 + h_sub];

    float4 acc = make_float4(0.f, 0.f, 0.f, 0.f);
    float sm = 0.f;
    int nfull = cnt & ~7;
    int i0 = start;
    for (; i0 < start + nfull; i0 += 8) {
        int s_l = esrc[i0 + e_sub];
        float w8 = __expf(lrelu(as[s_l * 8 + h_sub] + adh));
        sm += w8;
        int se[8]; float we[8];
        #pragma unroll
        for (int e = 0; e < 8; e++) {
            se[e] = __shfl(s_l, e * 8);
            we[e] = __shfl(w8, e * 8 + ch_head);
        }
        ushort4 hv[8];
        #pragma unroll
        for (int e = 0; e < 8; e++)
            hv[e] = *reinterpret_cast<const ushort4*>(&hfeat[(size_t)se[e] * 256 + lane4]);
        #pragma unroll
        for (int e = 0; e < 8; e++) {
            acc.x = fmaf(we[e], bf2f(hv[e].x), acc.x);
            acc.y = fmaf(we[e], bf2f(hv[e].y), acc.y);
            acc.z = fmaf(we[e], bf2f(hv[e].z), acc.z);
            acc.w = fmaf(we[e], bf2f(hv[e].w), acc.w);
        }
    }
    int rem = cnt - nfull;
    if (rem) {
        int idx = i0 + e_sub;
        int s_l = esrc[idx < end ? idx : end - 1];
        float w8 = (idx < end) ? __expf(lrelu(as[s_l * 8 + h_sub] + adh)) : 0.f;
        sm += w8;
        #pragma unroll
        for (int e = 0; e < 8; e++) {
            if (e < rem) {
                int se = __shfl(s_l, e * 8);
                float we = __shfl(w8, e * 8 + ch_head);
                ushort4 hv = *reinterpret_cast<const ushort4*>(&hfeat[(size_t)se * 256 + lane4]);
                acc.x = fmaf(we, bf2f(hv.x), acc.x);
                acc.y = fmaf(we, bf2f(hv.y), acc.y);
                acc.z = fmaf(we, bf2f(hv.z), acc.z);
                acc.w = fmaf(we, bf2f(hv.w), acc.w);
            }
        }
    }
    #pragma unroll
    for (int off = 8; off < 64; off <<= 1) sm += __shfl_xor(sm, off);
    float il = 1.f / (sm + 1e-16f);
    float il_c = __shfl(il, ch_head);

    float4 bv  = *reinterpret_cast<const float4*>(&bias[lane4]);
    float4 gv  = *reinterpret_cast<const float4*>(&bn_g[lane4]);
    float4 bbv = *reinterpret_cast<const float4*>(&bn_b[lane4]);
    float4 mv  = *reinterpret_cast<const float4*>(&bn_m[lane4]);
    float4 vv  = *reinterpret_cast<const float4*>(&bn_v[lane4]);
    float o[4] = {acc.x * il_c + bv.x, acc.y * il_c + bv.y,
                  acc.z * il_c + bv.z, acc.w * il_c + bv.w};
    float g[4] = {gv.x, gv.y, gv.z, gv.w}, bb[4] = {bbv.x, bbv.y, bbv.z, bbv.w};
    float m[4] = {mv.x, mv.y, mv.z, mv.w}, vr[4] = {vv.x, vv.y, vv.z, vv.w};
    float sk[4] = {0.f, 0.f, 0.f, 0.f};
    if (MODE == 1) {
        float4 s4 = *reinterpret_cast<const float4*>(&skip[(size_t)n * 256 + lane4]);
        sk[0] = s4.x; sk[1] = s4.y; sk[2] = s4.z; sk[3] = s4.w;
    }
    ushort4 res;
    unsigned short* rp = &res.x;
    #pragma unroll
    for (int j = 0; j < 4; j++) {
        float val = (o[j] - m[j]) * rsqrtf(vr[j] + BN_EPS) * g[j] + bb[j];
        val = val > 0.f ? val : (__expf(val) - 1.f);
        val += sk[j];
        rp[j] = f2bf(val);
    }
    *reinterpret_cast<ushort4*>(&out[(size_t)n * 256 + lane4]) = res;
}

// ---------------------------------------------------------------- aggregation H=1,C=32
__global__ __launch_bounds__(256) void agg32(const unsigned short* __restrict__ h3,
                                             const float* __restrict__ as,
                                             const float* __restrict__ ad,
                                             const int* __restrict__ indptr,
                                             const int* __restrict__ esrc,
                                             const float* __restrict__ b3,
                                             const float* __restrict__ xs,
                                             float* __restrict__ out, int N) {
    int t = threadIdx.x;
    int n = blockIdx.x * 4 + (t >> 6);
    if (n >= N) return;
    int lane = t & 63;
    int e_sub = lane >> 3, c4 = (lane & 7) * 4;
    int start = indptr[n], end = indptr[n + 1];
    float adn = ad[n];

    float4 acc = make_float4(0.f, 0.f, 0.f, 0.f);
    float sm = 0.f;
    int i0 = start;
    for (; i0 + 16 <= end; i0 += 16) {
        int sA = esrc[i0 + e_sub];
        int sB = esrc[i0 + 8 + e_sub];
        float wA = __expf(lrelu(as[sA] + adn));
        float wB = __expf(lrelu(as[sB] + adn));
        sm += wA + wB;
        ushort4 hA = *reinterpret_cast<const ushort4*>(&h3[(size_t)sA * 32 + c4]);
        ushort4 hB = *reinterpret_cast<const ushort4*>(&h3[(size_t)sB * 32 + c4]);
        acc.x = fmaf(wA, bf2f(hA.x), acc.x); acc.y = fmaf(wA, bf2f(hA.y), acc.y);
        acc.z = fmaf(wA, bf2f(hA.z), acc.z); acc.w = fmaf(wA, bf2f(hA.w), acc.w);
        acc.x = fmaf(wB, bf2f(hB.x), acc.x); acc.y = fmaf(wB, bf2f(hB.y), acc.y);
        acc.z = fmaf(wB, bf2f(hB.z), acc.z); acc.w = fmaf(wB, bf2f(hB.w), acc.w);
    }
    for (; i0 < end; i0 += 8) {
        int idx = i0 + e_sub;
        bool valid = idx < end;
        if (valid) {
            int s = esrc[idx];
            float w = __expf(lrelu(as[s] + adn));
            sm += w;
            ushort4 hv = *reinterpret_cast<const ushort4*>(&h3[(size_t)s * 32 + c4]);
            acc.x = fmaf(w, bf2f(hv.x), acc.x);
            acc.y = fmaf(w, bf2f(hv.y), acc.y);
            acc.z = fmaf(w, bf2f(hv.z), acc.z);
            acc.w = fmaf(w, bf2f(hv.w), acc.w);
        }
    }
    #pragma unroll
    for (int off = 8; off < 64; off <<= 1) {
        sm    += __shfl_xor(sm, off);
        acc.x += __shfl_xor(acc.x, off);
        acc.y += __shfl_xor(acc.y, off);
        acc.z += __shfl_xor(acc.z, off);
        acc.w += __shfl_xor(acc.w, off);
    }
    if (e_sub == 0) {
        float il = 1.f / (sm + 1e-16f);
        float4 bv = *reinterpret_cast<const float4*>(&b3[c4]);
        float4 xv = *reinterpret_cast<const float4*>(&xs[(size_t)n * 32 + c4]);
        float4 o;
        o.x = acc.x * il + bv.x + xv.x;
        o.y = acc.y * il + bv.y + xv.y;
        o.z = acc.z * il + bv.z + xv.z;
        o.w = acc.w * il + bv.w + xv.w;
        *reinterpret_cast<float4*>(&out[(size_t)n * 32 + c4]) = o;
    }
}

// ---------------------------------------------------------------- launch
extern "C" void kernel_launch(void* const* d_in, const int* in_sizes, int n_in,
                              void* d_out, int out_size, void* d_ws, size_t ws_size,
                              hipStream_t stream) {
    const float* x      = (const float*)d_in[0];
    const int*   eidx   = (const int*)  d_in[1];
    const float* W1     = (const float*)d_in[2];
    const float* a_src1 = (const float*)d_in[3];
    const float* a_dst1 = (const float*)d_in[4];
    const float* b1     = (const float*)d_in[5];
    const float* bn1_g  = (const float*)d_in[6];
    const float* bn1_b  = (const float*)d_in[7];
    const float* bn1_m  = (const float*)d_in[8];
    const float* bn1_v  = (const float*)d_in[9];
    const float* W2     = (const float*)d_in[10];
    const float* a_src2 = (const float*)d_in[11];
    const float* a_dst2 = (const float*)d_in[12];
    const float* b2     = (const float*)d_in[13];
    const float* bn2_g  = (const float*)d_in[14];
    const float* bn2_b  = (const float*)d_in[15];
    const float* bn2_m  = (const float*)d_in[16];
    const float* bn2_v  = (const float*)d_in[17];
    const float* W3     = (const float*)d_in[18];
    const float* a_src3 = (const float*)d_in[19];
    const float* a_dst3 = (const float*)d_in[20];
    const float* b3     = (const float*)d_in[21];
    const float* Ws1    = (const float*)d_in[22];
    const float* bs1    = (const float*)d_in[23];
    const float* Ws2    = (const float*)d_in[24];
    const float* bs2    = (const float*)d_in[25];

    const int N = in_sizes[0] / 128;   // 50000
    const int E = in_sizes[1] / 2;     // 800000
    const int Etot = E + N;
    const int* srcl = eidx;
    const int* dstl = eidx + E;

    char* ws = (char*)d_ws;
    size_t off = 0;
    auto alloc = [&](size_t bytes) -> void* {
        void* p = ws + off;
        off += (bytes + 255) & ~(size_t)255;
        return p;
    };
    unsigned short* xb    = (unsigned short*)alloc((size_t)N * 128 * 2);
    float*          feat  = (float*)alloc((size_t)N * 256 * 4);          // x0 skip (fp32)
    unsigned short* hbuf  = (unsigned short*)alloc((size_t)N * 256 * 2); // gemm h output
    unsigned short* h2b   = (unsigned short*)alloc((size_t)N * 256 * 2); // layer-1 agg out
    unsigned short* featb = (unsigned short*)alloc((size_t)N * 256 * 2); // layer-2 agg out
    float*          xsbuf = (float*)alloc((size_t)N * 32 * 4);
    unsigned short* h3b   = (unsigned short*)alloc((size_t)N * 32 * 2);
    float*          asb   = (float*)alloc((size_t)N * 8 * 4);
    float*          adb   = (float*)alloc((size_t)N * 8 * 4);
    unsigned short* Wcat  = (unsigned short*)alloc((size_t)512 * 128 * 2); // [W1t; Ws1t]
    unsigned short* Ws2t  = (unsigned short*)alloc((size_t)256 * 32 * 2);
    unsigned short* W2t   = (unsigned short*)alloc((size_t)256 * 256 * 2);
    unsigned short* W3t   = (unsigned short*)alloc((size_t)256 * 32 * 2);
    int* counts = (int*)alloc((size_t)N * 4);
    int* cursor = (int*)alloc((size_t)N * 4);
    int* indptr = (int*)alloc((size_t)(N + 1) * 4);
    int* bsums  = (int*)alloc(256 * 4);
    int* esrc   = (int*)alloc((size_t)Etot * 4);
    (void)ws_size; (void)n_in; (void)out_size;

    // ---- CSR by dst
    hipMemsetAsync(counts, 0, (size_t)N * 4, stream);
    int ceb = (Etot + 255) / 256;
    int nb  = (N + 255) / 256;
    count_kernel<<<ceb, 256, 0, stream>>>(dstl, E, N, counts);
    scan1<<<nb, 256, 0, stream>>>(counts, cursor, bsums, N);
    scan2<<<1, 256, 0, stream>>>(bsums, nb);
    scan3<<<nb, 256, 0, stream>>>(cursor, bsums, counts, indptr, cursor, N);
    fill_kernel<<<ceb, 256, 0, stream>>>(srcl, dstl, E, N, cursor, esrc);

    // ---- convert inputs
    f32_to_bf16<<<((N * 128 / 4) + 255) / 256, 256, 0, stream>>>(x, xb, N * 128 / 4);
    transpose_bf16<<<(128 * 256 + 255) / 256, 256, 0, stream>>>(W1, Wcat, 128, 256);
    transpose_bf16<<<(128 * 256 + 255) / 256, 256, 0, stream>>>(Ws1, Wcat + 256 * 128, 128, 256);
    transpose_bf16<<<(256 * 32 + 255) / 256, 256, 0, stream>>>(Ws2, Ws2t, 256, 32);
    transpose_bf16<<<(256 * 256 + 255) / 256, 256, 0, stream>>>(W2, W2t, 256, 256);
    transpose_bf16<<<(256 * 32 + 255) / 256, 256, 0, stream>>>(W3, W3t, 256, 32);

    int gy64 = (N + 63) / 64;
    int gy128 = (N + 127) / 128;
    int gn4 = (N + 3) / 4;

    // ---- layer 1: fused [h1 | x0] = x @ [W1 | Ws1]
    gemm_tile<<<dim3(4, gy128), 256, 0, stream>>>(xb, Wcat, hbuf, feat, bs1,
                                                  N, 128, 512, 256, 256, 256);
    alpha256<<<gn4, 256, 0, stream>>>(hbuf, a_src1, a_dst1, asb, adb, N);
    agg256<1><<<gn4, 256, 0, stream>>>(hbuf, asb, adb, indptr, esrc, b1,
                                       bn1_g, bn1_b, bn1_m, bn1_v, feat, h2b, N);

    // ---- layer 2
    gemm_bf16<32, float><<<dim3(1, gy64), 256, 0, stream>>>(h2b, Ws2t, bs2, xsbuf, N, 256, 32);
    gemm_tile<<<dim3(2, gy128), 256, 0, stream>>>(h2b, W2t, hbuf, nullptr, nullptr,
                                                  N, 256, 256, 256, 256, 0);
    alpha256<<<gn4, 256, 0, stream>>>(hbuf, a_src2, a_dst2, asb, adb, N);
    agg256<0><<<gn4, 256, 0, stream>>>(hbuf, asb, adb, indptr, esrc, b2,
                                       bn2_g, bn2_b, bn2_m, bn2_v, nullptr, featb, N);

    // ---- layer 3
    gemm_bf16<32, unsigned short><<<dim3(1, gy64), 256, 0, stream>>>(featb, W3t, nullptr, h3b, N, 256, 32);
    alpha32<<<(N + 31) / 32, 256, 0, stream>>>(h3b, a_src3, a_dst3, asb, adb, N);
    agg32<<<gn4, 256, 0, stream>>>(h3b, asb, adb, indptr, esrc, b3, xsbuf,
                                   (float*)d_out, N);
}

// Round 7
// 495.048 us; speedup vs baseline: 1.4280x; 1.0396x over previous
//
#include <hip/hip_runtime.h>
#include <hip/hip_bf16.h>

#define NEG_SLOPE 0.2f
#define BN_EPS 1e-5f

typedef __attribute__((ext_vector_type(8))) short bf16x8;
typedef __attribute__((ext_vector_type(4))) float f32x4;

__device__ __forceinline__ float bf2f(unsigned short u) {
    union { unsigned int i; float f; } x;
    x.i = ((unsigned int)u) << 16;
    return x.f;
}
__device__ __forceinline__ unsigned short f2bf(float f) {
    __hip_bfloat16 b = __float2bfloat16(f);
    return *reinterpret_cast<unsigned short*>(&b);
}
__device__ __forceinline__ float lrelu(float v) {
    return v > 0.f ? v : NEG_SLOPE * v;
}
__device__ __forceinline__ void gload_lds16(const void* g, void* l) {
    __builtin_amdgcn_global_load_lds(
        (const __attribute__((address_space(1))) unsigned int*)(g),
        (__attribute__((address_space(3))) unsigned int*)(l),
        16, 0, 0);
}

// ---------------------------------------------------------------- CSR build
__global__ __launch_bounds__(256) void count_kernel(const int* __restrict__ dstl,
                                                    int E, int N, int* __restrict__ counts) {
    int i = blockIdx.x * 256 + threadIdx.x;
    if (i < E + N) {
        int d = (i < E) ? dstl[i] : (i - E);
        atomicAdd(&counts[d], 1);
    }
}

__device__ __forceinline__ int block_scan_incl(int v, int t) {
    int lane = t & 63, w = t >> 6;
    int sv = v;
    #pragma unroll
    for (int off = 1; off < 64; off <<= 1) {
        int u = __shfl_up(sv, off);
        if (lane >= off) sv += u;
    }
    __shared__ int ws[4];
    if (lane == 63) ws[w] = sv;
    __syncthreads();
    if (t == 0) {
        int a = 0;
        #pragma unroll
        for (int k = 0; k < 4; k++) { int x = ws[k]; ws[k] = a; a += x; }
    }
    __syncthreads();
    return sv + ws[w];
}

__global__ __launch_bounds__(256) void scan1(const int* __restrict__ counts,
                                             int* __restrict__ tmp,
                                             int* __restrict__ bsums, int n) {
    int t = threadIdx.x, i = blockIdx.x * 256 + t;
    int v = (i < n) ? counts[i] : 0;
    int incl = block_scan_incl(v, t);
    if (i < n) tmp[i] = incl;
    if (t == 255) bsums[blockIdx.x] = incl;
}

__global__ __launch_bounds__(256) void scan2(int* __restrict__ bsums, int nb) {
    int t = threadIdx.x;
    int v = (t < nb) ? bsums[t] : 0;
    int incl = block_scan_incl(v, t);
    if (t < nb) bsums[t] = incl - v;
}

__global__ __launch_bounds__(256) void scan3(const int* __restrict__ tmp,
                                             const int* __restrict__ bsums,
                                             const int* __restrict__ counts,
                                             int* __restrict__ indptr,
                                             int* __restrict__ cursor, int n) {
    int i = blockIdx.x * 256 + threadIdx.x;
    if (i < n) {
        int incl = tmp[i] + bsums[i >> 8];
        indptr[i + 1] = incl;
        cursor[i] = incl - counts[i];
        if (i == 0) indptr[0] = 0;
    }
}

__global__ __launch_bounds__(256) void fill_kernel(const int* __restrict__ srcl,
                                                   const int* __restrict__ dstl,
                                                   int E, int N,
                                                   int* __restrict__ cursor,
                                                   int* __restrict__ esrc) {
    int i = blockIdx.x * 256 + threadIdx.x;
    if (i < E + N) {
        int s, d;
        if (i < E) { s = srcl[i]; d = dstl[i]; }
        else       { s = d = i - E; }
        int slot = atomicAdd(&cursor[d], 1);
        esrc[slot] = s;
    }
}

// ---------------------------------------------------------------- converts
__global__ __launch_bounds__(256) void f32_to_bf16(const float* __restrict__ src,
                                                   unsigned short* __restrict__ dst, int n4) {
    int i = blockIdx.x * 256 + threadIdx.x;
    if (i < n4) {
        float4 v = reinterpret_cast<const float4*>(src)[i];
        ushort4 o;
        o.x = f2bf(v.x); o.y = f2bf(v.y); o.z = f2bf(v.z); o.w = f2bf(v.w);
        reinterpret_cast<ushort4*>(dst)[i] = o;
    }
}

// All weight transposes in one dispatch.
// Wcat1[512 x 128] = [W1^T ; Ws1^T]; Wcat2[288 x 256] = [W2^T ; Ws2^T]; W3t[32 x 256].
__global__ __launch_bounds__(256) void prep_weights(const float* __restrict__ W1,
                                                    const float* __restrict__ Ws1,
                                                    const float* __restrict__ W2,
                                                    const float* __restrict__ Ws2,
                                                    const float* __restrict__ W3,
                                                    unsigned short* __restrict__ Wcat1,
                                                    unsigned short* __restrict__ Wcat2,
                                                    unsigned short* __restrict__ W3t) {
    int i = blockIdx.x * 256 + threadIdx.x;
    if (i < 32768) {                       // W1^T: 256 rows x 128
        int m = i >> 7, k = i & 127;
        Wcat1[i] = f2bf(W1[k * 256 + m]);
    } else if (i < 65536) {                // Ws1^T: rows 256..511
        int j = i - 32768; int m = j >> 7, k = j & 127;
        Wcat1[32768 + j] = f2bf(Ws1[k * 256 + m]);
    } else if (i < 131072) {               // W2^T: 256 rows x 256
        int j = i - 65536; int m = j >> 8, k = j & 255;
        Wcat2[j] = f2bf(W2[k * 256 + m]);
    } else if (i < 139264) {               // Ws2^T: rows 256..287
        int j = i - 131072; int m = j >> 8, k = j & 255;
        Wcat2[65536 + j] = f2bf(Ws2[k * 32 + m]);
    } else if (i < 147456) {               // W3^T: 32 rows x 256
        int j = i - 139264; int m = j >> 8, k = j & 255;
        W3t[j] = f2bf(W3[k * 32 + m]);
    }
}

// ---------------------------------------------------------------- tiled MFMA GEMM
// C[M x NCtot] = A[M x K](bf16) @ B, Bt[NCtot x K] = B^T (bf16).
// 128x128 tile, BK=32, double-buffered LDS via global_load_lds(16B).
// Epilogue split: col < split -> bf16 outBf; col >= split -> fp32 outF + biasF.
__global__ __launch_bounds__(256) void gemm_tile(const unsigned short* __restrict__ A,
                                                 const unsigned short* __restrict__ Bt,
                                                 unsigned short* __restrict__ outBf,
                                                 float* __restrict__ outF,
                                                 const float* __restrict__ biasF,
                                                 int M, int K, int NCtot, int split,
                                                 int ldBf, int ldF) {
    __shared__ __align__(16) char smem[2][2][8192];
    int t = threadIdx.x;
    int w = t >> 6, lane = t & 63;
    int l16 = lane & 15, quad = lane >> 4;
    int warp_r = w >> 1, warp_c = w & 1;
    int rowBase = blockIdx.y * 128;
    int colBase = blockIdx.x * 128;

    int row_l = t & 127;
    int jchunk = t >> 7;
    int arow_st = rowBase + row_l; if (arow_st >= M) arow_st = M - 1;
    int bcol_st = colBase + row_l; if (bcol_st >= NCtot) bcol_st = NCtot - 1;
    const unsigned short* aRow = A + (size_t)arow_st * K;
    const unsigned short* bRow = Bt + (size_t)bcol_st * K;

    f32x4 acc[4][4];
    #pragma unroll
    for (int i = 0; i < 4; i++)
        #pragma unroll
        for (int j = 0; j < 4; j++) acc[i][j] = (f32x4){0.f, 0.f, 0.f, 0.f};

    auto stage = [&](int buf, int k0) {
        #pragma unroll
        for (int j = 0; j < 2; j++) {
            int chunk = j * 2 + jchunk;
            gload_lds16(aRow + k0 + chunk * 8, &smem[buf][0][(size_t)j * 4096 + (size_t)t * 16]);
            gload_lds16(bRow + k0 + chunk * 8, &smem[buf][1][(size_t)j * 4096 + (size_t)t * 16]);
        }
    };

    stage(0, 0);
    __syncthreads();
    int niter = K >> 5;
    for (int it = 0; it < niter; ++it) {
        if (it + 1 < niter) stage((it + 1) & 1, (it + 1) << 5);
        const char* Ab = &smem[it & 1][0][0];
        const char* Bb = &smem[it & 1][1][0];
        bf16x8 a[4], b[4];
        #pragma unroll
        for (int i = 0; i < 4; i++)
            a[i] = *reinterpret_cast<const bf16x8*>(Ab + quad * 2048 + (warp_r * 64 + i * 16 + l16) * 16);
        #pragma unroll
        for (int j = 0; j < 4; j++)
            b[j] = *reinterpret_cast<const bf16x8*>(Bb + quad * 2048 + (warp_c * 64 + j * 16 + l16) * 16);
        #pragma unroll
        for (int i = 0; i < 4; i++)
            #pragma unroll
            for (int j = 0; j < 4; j++)
                acc[i][j] = __builtin_amdgcn_mfma_f32_16x16x32_bf16(a[i], b[j], acc[i][j], 0, 0, 0);
        __syncthreads();
    }

    #pragma unroll
    for (int i = 0; i < 4; i++) {
        #pragma unroll
        for (int r = 0; r < 4; r++) {
            int row = rowBase + warp_r * 64 + i * 16 + quad * 4 + r;
            if (row >= M) continue;
            #pragma unroll
            for (int j = 0; j < 4; j++) {
                int c = colBase + warp_c * 64 + j * 16 + l16;
                if (c >= NCtot) continue;
                float v = acc[i][j][r];
                if (c < split) outBf[(size_t)row * ldBf + c] = f2bf(v);
                else           outF[(size_t)row * ldF + (c - split)] = v + biasF[c - split];
            }
        }
    }
}

// ---------------------------------------------------------------- register-direct GEMM (skinny NC=32)
template <int NCT, typename OutT>
__global__ __launch_bounds__(256) void gemm_bf16(const unsigned short* __restrict__ A,
                                                 const unsigned short* __restrict__ Bt,
                                                 const float* __restrict__ bias,
                                                 OutT* __restrict__ C,
                                                 int M, int K, int NC) {
    constexpr int NF = NCT / 16;
    int t = threadIdx.x;
    int w = t >> 6, lane = t & 63;
    int l16 = lane & 15, quad = lane >> 4;
    int rowBase = blockIdx.y * 64 + w * 16;
    int colBase = blockIdx.x * NCT;

    f32x4 acc[NF];
    #pragma unroll
    for (int f = 0; f < NF; f++) acc[f] = (f32x4){0.f, 0.f, 0.f, 0.f};

    int arow = rowBase + l16;
    if (arow >= M) arow = M - 1;
    const unsigned short* aptr = A + (size_t)arow * K + quad * 8;

    for (int k0 = 0; k0 < K; k0 += 32) {
        bf16x8 af = *reinterpret_cast<const bf16x8*>(aptr + k0);
        #pragma unroll
        for (int f = 0; f < NF; f++) {
            int col = colBase + f * 16 + l16;
            bf16x8 bf = *reinterpret_cast<const bf16x8*>(&Bt[(size_t)col * K + k0 + quad * 8]);
            acc[f] = __builtin_amdgcn_mfma_f32_16x16x32_bf16(af, bf, acc[f], 0, 0, 0);
        }
    }

    #pragma unroll
    for (int f = 0; f < NF; f++) {
        int col = colBase + f * 16 + l16;
        float bv = bias ? bias[col] : 0.f;
        #pragma unroll
        for (int r = 0; r < 4; r++) {
            int row = rowBase + quad * 4 + r;
            if (row < M) {
                float v = acc[f][r] + bv;
                if constexpr (sizeof(OutT) == 2) C[(size_t)row * NC + col] = (OutT)f2bf(v);
                else                             C[(size_t)row * NC + col] = v;
            }
        }
    }
}

// ---------------------------------------------------------------- alpha (H=8,C=32), wave/node
__global__ __launch_bounds__(256) void alpha256(const unsigned short* __restrict__ h,
                                                const float* __restrict__ a_s,
                                                const float* __restrict__ a_d,
                                                float* __restrict__ as_out,
                                                float* __restrict__ ad_out, int N) {
    int t = threadIdx.x;
    int n = blockIdx.x * 4 + (t >> 6);
    if (n >= N) return;
    int lane = t & 63, lane4 = lane * 4;
    ushort4 hv = *reinterpret_cast<const ushort4*>(&h[(size_t)n * 256 + lane4]);
    float4 sv = *reinterpret_cast<const float4*>(&a_s[lane4]);
    float4 dv = *reinterpret_cast<const float4*>(&a_d[lane4]);
    float h0 = bf2f(hv.x), h1 = bf2f(hv.y), h2 = bf2f(hv.z), h3 = bf2f(hv.w);
    float va = h0 * sv.x + h1 * sv.y + h2 * sv.z + h3 * sv.w;
    float vd = h0 * dv.x + h1 * dv.y + h2 * dv.z + h3 * dv.w;
    #pragma unroll
    for (int off = 1; off < 8; off <<= 1) {
        va += __shfl_xor(va, off);
        vd += __shfl_xor(vd, off);
    }
    if ((lane & 7) == 0) {
        as_out[n * 8 + (lane >> 3)] = va;
        ad_out[n * 8 + (lane >> 3)] = vd;
    }
}

// ---------------------------------------------------------------- alpha (H=1,C=32), 8 nodes/wave
__global__ __launch_bounds__(256) void alpha32(const unsigned short* __restrict__ h,
                                               const float* __restrict__ a_s,
                                               const float* __restrict__ a_d,
                                               float* __restrict__ as_out,
                                               float* __restrict__ ad_out, int N) {
    int t = threadIdx.x;
    int lane = t & 63;
    int n = blockIdx.x * 32 + (t >> 6) * 8 + (lane >> 3);
    int c4 = (lane & 7) * 4;
    if (n >= N) return;
    ushort4 hv = *reinterpret_cast<const ushort4*>(&h[(size_t)n * 32 + c4]);
    float4 sv = *reinterpret_cast<const float4*>(&a_s[c4]);
    float4 dv = *reinterpret_cast<const float4*>(&a_d[c4]);
    float h0 = bf2f(hv.x), h1 = bf2f(hv.y), h2 = bf2f(hv.z), h3 = bf2f(hv.w);
    float va = h0 * sv.x + h1 * sv.y + h2 * sv.z + h3 * sv.w;
    float vd = h0 * dv.x + h1 * dv.y + h2 * dv.z + h3 * dv.w;
    #pragma unroll
    for (int off = 1; off < 8; off <<= 1) {
        va += __shfl_xor(va, off);
        vd += __shfl_xor(vd, off);
    }
    if ((lane & 7) == 0) {
        as_out[n] = va;
        ad_out[n] = vd;
    }
}

// ---------------------------------------------------------------- aggregation H=8,C=32
// One wave per node, single pass, SOFTWARE-PIPELINED: next iteration's
// esrc/as/exp chain is issued before the current 8 hfeat gathers, so its
// ~400cy latency overlaps the gather+FMA block. Inline shuffles (no se/we
// arrays) keep VGPR low (R4 lesson: arrays -> spill).
template <int MODE>
__global__ __launch_bounds__(256) void agg256(const unsigned short* __restrict__ hfeat,
                                              const float* __restrict__ as,
                                              const float* __restrict__ ad,
                                              const int* __restrict__ indptr,
                                              const int* __restrict__ esrc,
                                              const float* __restrict__ bias,
                                              const float* __restrict__ bn_g,
                                              const float* __restrict__ bn_b,
                                              const float* __restrict__ bn_m,
                                              const float* __restrict__ bn_v,
                                              const float* __restrict__ skip,
                                              unsigned short* __restrict__ out, int N) {
    int t = threadIdx.x;
    int n = blockIdx.x * 4 + (t >> 6);
    if (n >= N) return;
    int lane = t & 63;
    int e_sub = lane >> 3, h_sub = lane & 7;
    int ch_head = lane >> 3;
    int lane4 = lane * 4;
    int start = indptr[n], end = indptr[n + 1];
    int cnt = end - start;

    float adh = ad[n * 8 + h_sub];

    float4 acc = make_float4(0.f, 0.f, 0.f, 0.f);
    float sm = 0.f;
    int nfull = cnt & ~7;
    int i0 = start;
    int s_l = 0; float w8 = 0.f;
    if (nfull) {
        s_l = esrc[i0 + e_sub];
        w8 = __expf(lrelu(as[s_l * 8 + h_sub] + adh));
    }
    while (i0 < start + nfull) {
        int s_cur = s_l;
        float w_cur = w8;
        i0 += 8;
        if (i0 < start + nfull) {           // prefetch next chain (uniform branch)
            s_l = esrc[i0 + e_sub];
            w8 = __expf(lrelu(as[s_l * 8 + h_sub] + adh));
        }
        sm += w_cur;
        ushort4 hv[8];
        #pragma unroll
        for (int e = 0; e < 8; e++) {
            int se = __shfl(s_cur, e * 8);
            hv[e] = *reinterpret_cast<const ushort4*>(&hfeat[(size_t)se * 256 + lane4]);
        }
        #pragma unroll
        for (int e = 0; e < 8; e++) {
            float we = __shfl(w_cur, e * 8 + ch_head);
            acc.x = fmaf(we, bf2f(hv[e].x), acc.x);
            acc.y = fmaf(we, bf2f(hv[e].y), acc.y);
            acc.z = fmaf(we, bf2f(hv[e].z), acc.z);
            acc.w = fmaf(we, bf2f(hv[e].w), acc.w);
        }
    }
    int rem = cnt - nfull;
    if (rem) {
        int idx = i0 + e_sub;
        int s_r = esrc[idx < end ? idx : end - 1];
        float w_r = (idx < end) ? __expf(lrelu(as[s_r * 8 + h_sub] + adh)) : 0.f;
        sm += w_r;
        #pragma unroll
        for (int e = 0; e < 8; e++) {
            if (e < rem) {
                int se = __shfl(s_r, e * 8);
                float we = __shfl(w_r, e * 8 + ch_head);
                ushort4 hv = *reinterpret_cast<const ushort4*>(&hfeat[(size_t)se * 256 + lane4]);
                acc.x = fmaf(we, bf2f(hv.x), acc.x);
                acc.y = fmaf(we, bf2f(hv.y), acc.y);
                acc.z = fmaf(we, bf2f(hv.z), acc.z);
                acc.w = fmaf(we, bf2f(hv.w), acc.w);
            }
        }
    }
    #pragma unroll
    for (int off = 8; off < 64; off <<= 1) sm += __shfl_xor(sm, off);
    float il = 1.f / (sm + 1e-16f);
    float il_c = __shfl(il, ch_head);

    float4 bv  = *reinterpret_cast<const float4*>(&bias[lane4]);
    float4 gv  = *reinterpret_cast<const float4*>(&bn_g[lane4]);
    float4 bbv = *reinterpret_cast<const float4*>(&bn_b[lane4]);
    float4 mv  = *reinterpret_cast<const float4*>(&bn_m[lane4]);
    float4 vv  = *reinterpret_cast<const float4*>(&bn_v[lane4]);
    float o[4] = {acc.x * il_c + bv.x, acc.y * il_c + bv.y,
                  acc.z * il_c + bv.z, acc.w * il_c + bv.w};
    float g[4] = {gv.x, gv.y, gv.z, gv.w}, bb[4] = {bbv.x, bbv.y, bbv.z, bbv.w};
    float m[4] = {mv.x, mv.y, mv.z, mv.w}, vr[4] = {vv.x, vv.y, vv.z, vv.w};
    float sk[4] = {0.f, 0.f, 0.f, 0.f};
    if (MODE == 1) {
        float4 s4 = *reinterpret_cast<const float4*>(&skip[(size_t)n * 256 + lane4]);
        sk[0] = s4.x; sk[1] = s4.y; sk[2] = s4.z; sk[3] = s4.w;
    }
    ushort4 res;
    unsigned short* rp = &res.x;
    #pragma unroll
    for (int j = 0; j < 4; j++) {
        float val = (o[j] - m[j]) * rsqrtf(vr[j] + BN_EPS) * g[j] + bb[j];
        val = val > 0.f ? val : (__expf(val) - 1.f);
        val += sk[j];
        rp[j] = f2bf(val);
    }
    *reinterpret_cast<ushort4*>(&out[(size_t)n * 256 + lane4]) = res;
}

// ---------------------------------------------------------------- aggregation H=1,C=32
__global__ __launch_bounds__(256) void agg32(const unsigned short* __restrict__ h3,
                                             const float* __restrict__ as,
                                             const float* __restrict__ ad,
                                             const int* __restrict__ indptr,
                                             const int* __restrict__ esrc,
                                             const float* __restrict__ b3,
                                             const float* __restrict__ xs,
                                             float* __restrict__ out, int N) {
    int t = threadIdx.x;
    int n = blockIdx.x * 4 + (t >> 6);
    if (n >= N) return;
    int lane = t & 63;
    int e_sub = lane >> 3, c4 = (lane & 7) * 4;
    int start = indptr[n], end = indptr[n + 1];
    float adn = ad[n];

    float4 acc = make_float4(0.f, 0.f, 0.f, 0.f);
    float sm = 0.f;
    int i0 = start;
    for (; i0 + 16 <= end; i0 += 16) {
        int sA = esrc[i0 + e_sub];
        int sB = esrc[i0 + 8 + e_sub];
        float wA = __expf(lrelu(as[sA] + adn));
        float wB = __expf(lrelu(as[sB] + adn));
        sm += wA + wB;
        ushort4 hA = *reinterpret_cast<const ushort4*>(&h3[(size_t)sA * 32 + c4]);
        ushort4 hB = *reinterpret_cast<const ushort4*>(&h3[(size_t)sB * 32 + c4]);
        acc.x = fmaf(wA, bf2f(hA.x), acc.x); acc.y = fmaf(wA, bf2f(hA.y), acc.y);
        acc.z = fmaf(wA, bf2f(hA.z), acc.z); acc.w = fmaf(wA, bf2f(hA.w), acc.w);
        acc.x = fmaf(wB, bf2f(hB.x), acc.x); acc.y = fmaf(wB, bf2f(hB.y), acc.y);
        acc.z = fmaf(wB, bf2f(hB.z), acc.z); acc.w = fmaf(wB, bf2f(hB.w), acc.w);
    }
    for (; i0 < end; i0 += 8) {
        int idx = i0 + e_sub;
        bool valid = idx < end;
        if (valid) {
            int s = esrc[idx];
            float w = __expf(lrelu(as[s] + adn));
            sm += w;
            ushort4 hv = *reinterpret_cast<const ushort4*>(&h3[(size_t)s * 32 + c4]);
            acc.x = fmaf(w, bf2f(hv.x), acc.x);
            acc.y = fmaf(w, bf2f(hv.y), acc.y);
            acc.z = fmaf(w, bf2f(hv.z), acc.z);
            acc.w = fmaf(w, bf2f(hv.w), acc.w);
        }
    }
    #pragma unroll
    for (int off = 8; off < 64; off <<= 1) {
        sm    += __shfl_xor(sm, off);
        acc.x += __shfl_xor(acc.x, off);
        acc.y += __shfl_xor(acc.y, off);
        acc.z += __shfl_xor(acc.z, off);
        acc.w += __shfl_xor(acc.w, off);
    }
    if (e_sub == 0) {
        float il = 1.f / (sm + 1e-16f);
        float4 bv = *reinterpret_cast<const float4*>(&b3[c4]);
        float4 xv = *reinterpret_cast<const float4*>(&xs[(size_t)n * 32 + c4]);
        float4 o;
        o.x = acc.x * il + bv.x + xv.x;
        o.y = acc.y * il + bv.y + xv.y;
        o.z = acc.z * il + bv.z + xv.z;
        o.w = acc.w * il + bv.w + xv.w;
        *reinterpret_cast<float4*>(&out[(size_t)n * 32 + c4]) = o;
    }
}

// ---------------------------------------------------------------- launch
extern "C" void kernel_launch(void* const* d_in, const int* in_sizes, int n_in,
                              void* d_out, int out_size, void* d_ws, size_t ws_size,
                              hipStream_t stream) {
    const float* x      = (const float*)d_in[0];
    const int*   eidx   = (const int*)  d_in[1];
    const float* W1     = (const float*)d_in[2];
    const float* a_src1 = (const float*)d_in[3];
    const float* a_dst1 = (const float*)d_in[4];
    const float* b1     = (const float*)d_in[5];
    const float* bn1_g  = (const float*)d_in[6];
    const float* bn1_b  = (const float*)d_in[7];
    const float* bn1_m  = (const float*)d_in[8];
    const float* bn1_v  = (const float*)d_in[9];
    const float* W2     = (const float*)d_in[10];
    const float* a_src2 = (const float*)d_in[11];
    const float* a_dst2 = (const float*)d_in[12];
    const float* b2     = (const float*)d_in[13];
    const float* bn2_g  = (const float*)d_in[14];
    const float* bn2_b  = (const float*)d_in[15];
    const float* bn2_m  = (const float*)d_in[16];
    const float* bn2_v  = (const float*)d_in[17];
    const float* W3     = (const float*)d_in[18];
    const float* a_src3 = (const float*)d_in[19];
    const float* a_dst3 = (const float*)d_in[20];
    const float* b3     = (const float*)d_in[21];
    const float* Ws1    = (const float*)d_in[22];
    const float* bs1    = (const float*)d_in[23];
    const float* Ws2    = (const float*)d_in[24];
    const float* bs2    = (const float*)d_in[25];

    const int N = in_sizes[0] / 128;   // 50000
    const int E = in_sizes[1] / 2;     // 800000
    const int Etot = E + N;
    const int* srcl = eidx;
    const int* dstl = eidx + E;

    char* ws = (char*)d_ws;
    size_t off = 0;
    auto alloc = [&](size_t bytes) -> void* {
        void* p = ws + off;
        off += (bytes + 255) & ~(size_t)255;
        return p;
    };
    unsigned short* xb    = (unsigned short*)alloc((size_t)N * 128 * 2);
    float*          feat  = (float*)alloc((size_t)N * 256 * 4);          // x0 skip (fp32)
    unsigned short* hbuf  = (unsigned short*)alloc((size_t)N * 256 * 2); // gemm h output
    unsigned short* h2b   = (unsigned short*)alloc((size_t)N * 256 * 2); // layer-1 agg out
    unsigned short* featb = (unsigned short*)alloc((size_t)N * 256 * 2); // layer-2 agg out
    float*          xsbuf = (float*)alloc((size_t)N * 32 * 4);
    unsigned short* h3b   = (unsigned short*)alloc((size_t)N * 32 * 2);
    float*          asb   = (float*)alloc((size_t)N * 8 * 4);
    float*          adb   = (float*)alloc((size_t)N * 8 * 4);
    unsigned short* Wcat1 = (unsigned short*)alloc((size_t)512 * 128 * 2); // [W1t; Ws1t]
    unsigned short* Wcat2 = (unsigned short*)alloc((size_t)288 * 256 * 2); // [W2t; Ws2t]
    unsigned short* W3t   = (unsigned short*)alloc((size_t)32 * 256 * 2);
    int* counts = (int*)alloc((size_t)N * 4);
    int* cursor = (int*)alloc((size_t)N * 4);
    int* indptr = (int*)alloc((size_t)(N + 1) * 4);
    int* bsums  = (int*)alloc(256 * 4);
    int* esrc   = (int*)alloc((size_t)Etot * 4);
    (void)ws_size; (void)n_in; (void)out_size;

    // ---- CSR by dst
    hipMemsetAsync(counts, 0, (size_t)N * 4, stream);
    int ceb = (Etot + 255) / 256;
    int nb  = (N + 255) / 256;
    count_kernel<<<ceb, 256, 0, stream>>>(dstl, E, N, counts);
    scan1<<<nb, 256, 0, stream>>>(counts, cursor, bsums, N);
    scan2<<<1, 256, 0, stream>>>(bsums, nb);
    scan3<<<nb, 256, 0, stream>>>(cursor, bsums, counts, indptr, cursor, N);
    fill_kernel<<<ceb, 256, 0, stream>>>(srcl, dstl, E, N, cursor, esrc);

    // ---- convert inputs
    f32_to_bf16<<<((N * 128 / 4) + 255) / 256, 256, 0, stream>>>(x, xb, N * 128 / 4);
    prep_weights<<<(147456 + 255) / 256, 256, 0, stream>>>(W1, Ws1, W2, Ws2, W3,
                                                           Wcat1, Wcat2, W3t);

    int gy64 = (N + 63) / 64;
    int gy128 = (N + 127) / 128;
    int gn4 = (N + 3) / 4;

    // ---- layer 1: fused [h1 | x0] = x @ [W1 | Ws1]
    gemm_tile<<<dim3(4, gy128), 256, 0, stream>>>(xb, Wcat1, hbuf, feat, bs1,
                                                  N, 128, 512, 256, 256, 256);
    alpha256<<<gn4, 256, 0, stream>>>(hbuf, a_src1, a_dst1, asb, adb, N);
    agg256<1><<<gn4, 256, 0, stream>>>(hbuf, asb, adb, indptr, esrc, b1,
                                       bn1_g, bn1_b, bn1_m, bn1_v, feat, h2b, N);

    // ---- layer 2: fused [h2 | xs] = h @ [W2 | Ws2]
    gemm_tile<<<dim3(3, gy128), 256, 0, stream>>>(h2b, Wcat2, hbuf, xsbuf, bs2,
                                                  N, 256, 288, 256, 256, 32);
    alpha256<<<gn4, 256, 0, stream>>>(hbuf, a_src2, a_dst2, asb, adb, N);
    agg256<0><<<gn4, 256, 0, stream>>>(hbuf, asb, adb, indptr, esrc, b2,
                                       bn2_g, bn2_b, bn2_m, bn2_v, nullptr, featb, N);

    // ---- layer 3
    gemm_bf16<32, unsigned short><<<dim3(1, gy64), 256, 0, stream>>>(featb, W3t, nullptr, h3b, N, 256, 32);
    alpha32<<<(N + 31) / 32, 256, 0, stream>>>(h3b, a_src3, a_dst3, asb, adb, N);
    agg32<<<gn4, 256, 0, stream>>>(h3b, asb, adb, indptr, esrc, b3, xsbuf,
                                   (float*)d_out, N);
}